// Round 1
// baseline (535.347 us; speedup 1.0000x reference)
//
#include <hip/hip_runtime.h>

#define N_NODES 50000
#define N_EDGES 800000
#define DIM     128
#define LAYERS  3

#define SCAN_BLOCKS ((N_NODES + 255) / 256)   // 196

// ---------------- CSR build ----------------

__global__ __launch_bounds__(256) void hist_kernel(const int* __restrict__ dst,
                                                   int* __restrict__ counts) {
    int e = blockIdx.x * 256 + threadIdx.x;
    if (e < N_EDGES) atomicAdd(&counts[dst[e]], 1);
}

// exclusive scan, pass A: per-block scan of 256-elem chunks
__global__ __launch_bounds__(256) void scan_a(int* __restrict__ data,
                                              int* __restrict__ bsums) {
    __shared__ int sh[256];
    int tid = threadIdx.x;
    int g = blockIdx.x * 256 + tid;
    int v = (g < N_NODES) ? data[g] : 0;
    sh[tid] = v;
    __syncthreads();
    for (int off = 1; off < 256; off <<= 1) {
        int t = (tid >= off) ? sh[tid - off] : 0;
        __syncthreads();
        sh[tid] += t;
        __syncthreads();
    }
    int incl = sh[tid];
    if (g < N_NODES) data[g] = incl - v;          // exclusive
    if (tid == 255) bsums[blockIdx.x] = incl;     // block total
}

// pass B: single-block exclusive scan of block sums (SCAN_BLOCKS <= 256)
__global__ __launch_bounds__(256) void scan_b(int* __restrict__ bsums) {
    __shared__ int sh[256];
    int tid = threadIdx.x;
    int v = (tid < SCAN_BLOCKS) ? bsums[tid] : 0;
    sh[tid] = v;
    __syncthreads();
    for (int off = 1; off < 256; off <<= 1) {
        int t = (tid >= off) ? sh[tid - off] : 0;
        __syncthreads();
        sh[tid] += t;
        __syncthreads();
    }
    if (tid < SCAN_BLOCKS) bsums[tid] = sh[tid] - v;  // exclusive
}

// pass C: add block offsets; set sentinel
__global__ __launch_bounds__(256) void scan_c(int* __restrict__ data,
                                              const int* __restrict__ bsums) {
    int g = blockIdx.x * 256 + threadIdx.x;
    if (g < N_NODES) data[g] += bsums[blockIdx.x];
    if (g == 0) data[N_NODES] = N_EDGES;
}

__global__ __launch_bounds__(256) void fill_kernel(const int* __restrict__ src,
                                                   const int* __restrict__ dst,
                                                   int* __restrict__ cursor,
                                                   int* __restrict__ srcs) {
    int e = blockIdx.x * 256 + threadIdx.x;
    if (e < N_EDGES) {
        int p = atomicAdd(&cursor[dst[e]], 1);
        srcs[p] = src[e];
    }
}

// ---------------- aggregation: one wave per node ----------------

__global__ __launch_bounds__(256) void aggregate_kernel(const float* __restrict__ x,
                                                        const int* __restrict__ row_start,
                                                        const int* __restrict__ srcs,
                                                        float* __restrict__ agg) {
    int wave = threadIdx.x >> 6;
    int lane = threadIdx.x & 63;
    int node = blockIdx.x * 4 + wave;
    if (node >= N_NODES) return;
    int beg = row_start[node];
    int end = row_start[node + 1];
    float ax = 0.f, ay = 0.f;
    int j = beg;
    for (; j + 1 < end; j += 2) {
        int s0 = srcs[j];
        int s1 = srcs[j + 1];
        float2 v0 = *(const float2*)(x + (size_t)s0 * DIM + lane * 2);
        float2 v1 = *(const float2*)(x + (size_t)s1 * DIM + lane * 2);
        ax += v0.x + v1.x;
        ay += v0.y + v1.y;
    }
    if (j < end) {
        int s = srcs[j];
        float2 v = *(const float2*)(x + (size_t)s * DIM + lane * 2);
        ax += v.x;
        ay += v.y;
    }
    float2 r;
    r.x = ax; r.y = ay;
    *(float2*)(agg + (size_t)node * DIM + lane * 2) = r;
}

// ---------------- GEMM: out = agg@Wr + x@Wroot + b ----------------
// Concatenated-K view: K=256 (k<128 -> agg/Wr, else x/Wroot).
// BM=64, BN=128, BK=32; 256 threads; per-thread 4 rows x 8 cols.

#define BM 64
#define BK 32

__global__ __launch_bounds__(256) void gemm_layer(const float* __restrict__ agg,
                                                  const float* __restrict__ xin,
                                                  const float* __restrict__ Wr,
                                                  const float* __restrict__ Wroot,
                                                  const float* __restrict__ bias,
                                                  float* __restrict__ out) {
    __shared__ float As[BM][BK + 1];   // +1 pad: conflict-free column reads
    __shared__ float Ws[BK][DIM];

    int tid = threadIdx.x;
    int tx = tid & 15;        // col group: cols tx*8 .. tx*8+7
    int ty = tid >> 4;        // row group: rows ty*4 .. ty*4+3
    int row0 = blockIdx.x * BM;

    float acc[4][8];
#pragma unroll
    for (int i = 0; i < 4; ++i)
#pragma unroll
        for (int j = 0; j < 8; ++j) acc[i][j] = 0.f;

    for (int kc = 0; kc < 256 / BK; ++kc) {
        int kbase = kc * BK;
        bool rel = (kbase < DIM);
        const float* Amat = rel ? agg : xin;
        const float* Wmat = rel ? Wr : Wroot;
        int k0 = rel ? kbase : (kbase - DIM);

        // stage A: 64 rows x 32 k  (512 float4, 2 per thread)
#pragma unroll
        for (int i = 0; i < 2; ++i) {
            int idx = tid + i * 256;       // 0..511
            int r = idx >> 3;              // 0..63
            int kk = (idx & 7) * 4;        // 0..28
            int gr = row0 + r;
            float4 v;
            if (gr < N_NODES) v = *(const float4*)(Amat + (size_t)gr * DIM + k0 + kk);
            else { v.x = v.y = v.z = v.w = 0.f; }
            As[r][kk + 0] = v.x;
            As[r][kk + 1] = v.y;
            As[r][kk + 2] = v.z;
            As[r][kk + 3] = v.w;
        }
        // stage W: 32 k x 128 cols (1024 float4, 4 per thread)
#pragma unroll
        for (int i = 0; i < 4; ++i) {
            int idx = tid + i * 256;       // 0..1023
            int r = idx >> 5;              // 0..31
            int c4 = (idx & 31) * 4;       // 0..124
            *(float4*)&Ws[r][c4] = *(const float4*)(Wmat + (size_t)(k0 + r) * DIM + c4);
        }
        __syncthreads();

#pragma unroll
        for (int k = 0; k < BK; ++k) {
            float a[4];
#pragma unroll
            for (int i = 0; i < 4; ++i) a[i] = As[ty * 4 + i][k];
            float4 w0 = *(float4*)&Ws[k][tx * 8];
            float4 w1 = *(float4*)&Ws[k][tx * 8 + 4];
            float w[8] = {w0.x, w0.y, w0.z, w0.w, w1.x, w1.y, w1.z, w1.w};
#pragma unroll
            for (int i = 0; i < 4; ++i)
#pragma unroll
                for (int j = 0; j < 8; ++j) acc[i][j] += a[i] * w[j];
        }
        __syncthreads();
    }

    // epilogue: + bias, store
    float4 b0 = *(const float4*)(bias + tx * 8);
    float4 b1 = *(const float4*)(bias + tx * 8 + 4);
#pragma unroll
    for (int i = 0; i < 4; ++i) {
        int gr = row0 + ty * 4 + i;
        if (gr < N_NODES) {
            float4 o0, o1;
            o0.x = acc[i][0] + b0.x; o0.y = acc[i][1] + b0.y;
            o0.z = acc[i][2] + b0.z; o0.w = acc[i][3] + b0.w;
            o1.x = acc[i][4] + b1.x; o1.y = acc[i][5] + b1.y;
            o1.z = acc[i][6] + b1.z; o1.w = acc[i][7] + b1.w;
            *(float4*)(out + (size_t)gr * DIM + tx * 8) = o0;
            *(float4*)(out + (size_t)gr * DIM + tx * 8 + 4) = o1;
        }
    }
}

// ---------------- launch ----------------

extern "C" void kernel_launch(void* const* d_in, const int* in_sizes, int n_in,
                              void* d_out, int out_size, void* d_ws, size_t ws_size,
                              hipStream_t stream) {
    const float* x0    = (const float*)d_in[0];
    const int*   ei    = (const int*)d_in[1];
    const float* Wrel  = (const float*)d_in[2];
    const float* Wroot = (const float*)d_in[3];
    const float* bvec  = (const float*)d_in[4];
    float* out = (float*)d_out;

    char* ws = (char*)d_ws;
    const size_t XBYTES = (size_t)N_NODES * DIM * sizeof(float);   // 25,600,000 (256-aligned)
    float* agg = (float*)ws;
    float* x1  = (float*)(ws + XBYTES);
    float* x2  = (float*)(ws + 2 * XBYTES);
    int* row_start = (int*)(ws + 3 * XBYTES);          // N_NODES+1 ints
    int* cursor    = row_start + 50176;                // padded
    int* srcs      = cursor + 50176;
    int* bsums     = srcs + N_EDGES;

    const int* src = ei;
    const int* dst = ei + N_EDGES;

    // CSR build (graph is layer-invariant; ws is re-poisoned every call)
    hipMemsetAsync(row_start, 0, (N_NODES + 1) * sizeof(int), stream);
    hist_kernel<<<(N_EDGES + 255) / 256, 256, 0, stream>>>(dst, row_start);
    scan_a<<<SCAN_BLOCKS, 256, 0, stream>>>(row_start, bsums);
    scan_b<<<1, 256, 0, stream>>>(bsums);
    scan_c<<<SCAN_BLOCKS, 256, 0, stream>>>(row_start, bsums);
    hipMemcpyAsync(cursor, row_start, N_NODES * sizeof(int),
                   hipMemcpyDeviceToDevice, stream);
    fill_kernel<<<(N_EDGES + 255) / 256, 256, 0, stream>>>(src, dst, cursor, srcs);

    const float* xin = x0;
    float* outs[LAYERS] = {x1, x2, out};
    for (int l = 0; l < LAYERS; ++l) {
        aggregate_kernel<<<(N_NODES + 3) / 4, 256, 0, stream>>>(xin, row_start, srcs, agg);
        gemm_layer<<<(N_NODES + BM - 1) / BM, 256, 0, stream>>>(
            agg, xin, Wrel + (size_t)l * DIM * DIM, Wroot + (size_t)l * DIM * DIM,
            bvec + (size_t)l * DIM, outs[l]);
        xin = outs[l];
    }
}

// Round 2
// 383.902 us; speedup vs baseline: 1.3945x; 1.3945x over previous
//
#include <hip/hip_runtime.h>

#define N_NODES 50000
#define N_EDGES 800000
#define DIM     128
#define LAYERS  3

#define SCAN_BLOCKS ((N_NODES + 255) / 256)   // 196

using short8 = __attribute__((ext_vector_type(8))) short;
using f32x4  = __attribute__((ext_vector_type(4))) float;

__device__ __forceinline__ unsigned short f2bf(float f) {
    unsigned int u = __builtin_bit_cast(unsigned int, f);
    unsigned int r = (u + 0x7fffu + ((u >> 16) & 1u)) >> 16;   // RTN-even
    return (unsigned short)r;
}
__device__ __forceinline__ float bfl(unsigned int u) {   // low 16 bits = bf16
    return __builtin_bit_cast(float, u << 16);
}
__device__ __forceinline__ float bfh(unsigned int u) {   // high 16 bits = bf16
    return __builtin_bit_cast(float, u & 0xffff0000u);
}

// ---------------- one-time converts ----------------

// x fp32 -> bf16, 8 elems/thread
__global__ __launch_bounds__(256) void convert_x(const float* __restrict__ x,
                                                 unsigned short* __restrict__ xb) {
    int t = blockIdx.x * 256 + threadIdx.x;
    size_t base = (size_t)t * 8;
    if (base >= (size_t)N_NODES * DIM) return;
    float4 v0 = *(const float4*)(x + base);
    float4 v1 = *(const float4*)(x + base + 4);
    uint4 o;
    o.x = ((unsigned)f2bf(v0.y) << 16) | f2bf(v0.x);
    o.y = ((unsigned)f2bf(v0.w) << 16) | f2bf(v0.z);
    o.z = ((unsigned)f2bf(v1.y) << 16) | f2bf(v1.x);
    o.w = ((unsigned)f2bf(v1.w) << 16) | f2bf(v1.z);
    *(uint4*)(xb + base) = o;
}

// W_rel/W_root fp32 [l][k][col] -> Wt bf16 [l][col][256] (k<128: rel, k>=128: root)
__global__ __launch_bounds__(256) void prep_w(const float* __restrict__ Wrel,
                                              const float* __restrict__ Wroot,
                                              unsigned short* __restrict__ Wt) {
    int t = blockIdx.x * 256 + threadIdx.x;   // 3*2*128*32 = 24576 threads
    if (t >= LAYERS * 2 * 128 * 32) return;
    int k4  = t & 31;
    int col = (t >> 5) & 127;
    int mat = (t >> 12) & 1;
    int l   = t >> 13;
    const float* W = (mat ? Wroot : Wrel) + (size_t)l * DIM * DIM;
    int k0 = k4 * 4;
    unsigned short b0 = f2bf(W[(size_t)(k0 + 0) * DIM + col]);
    unsigned short b1 = f2bf(W[(size_t)(k0 + 1) * DIM + col]);
    unsigned short b2 = f2bf(W[(size_t)(k0 + 2) * DIM + col]);
    unsigned short b3 = f2bf(W[(size_t)(k0 + 3) * DIM + col]);
    uint2 o;
    o.x = ((unsigned)b1 << 16) | b0;
    o.y = ((unsigned)b3 << 16) | b2;
    *(uint2*)(Wt + (size_t)l * 128 * 256 + (size_t)col * 256 + mat * 128 + k0) = o;
}

// ---------------- CSR build ----------------

__global__ __launch_bounds__(256) void hist_kernel(const int* __restrict__ dst,
                                                   int* __restrict__ counts) {
    int e = blockIdx.x * 256 + threadIdx.x;
    if (e < N_EDGES) atomicAdd(&counts[dst[e]], 1);
}

__global__ __launch_bounds__(256) void scan_a(int* __restrict__ data,
                                              int* __restrict__ bsums) {
    __shared__ int sh[256];
    int tid = threadIdx.x;
    int g = blockIdx.x * 256 + tid;
    int v = (g < N_NODES) ? data[g] : 0;
    sh[tid] = v;
    __syncthreads();
    for (int off = 1; off < 256; off <<= 1) {
        int t = (tid >= off) ? sh[tid - off] : 0;
        __syncthreads();
        sh[tid] += t;
        __syncthreads();
    }
    int incl = sh[tid];
    if (g < N_NODES) data[g] = incl - v;
    if (tid == 255) bsums[blockIdx.x] = incl;
}

__global__ __launch_bounds__(256) void scan_b(int* __restrict__ bsums) {
    __shared__ int sh[256];
    int tid = threadIdx.x;
    int v = (tid < SCAN_BLOCKS) ? bsums[tid] : 0;
    sh[tid] = v;
    __syncthreads();
    for (int off = 1; off < 256; off <<= 1) {
        int t = (tid >= off) ? sh[tid - off] : 0;
        __syncthreads();
        sh[tid] += t;
        __syncthreads();
    }
    if (tid < SCAN_BLOCKS) bsums[tid] = sh[tid] - v;
}

__global__ __launch_bounds__(256) void scan_c(int* __restrict__ data,
                                              const int* __restrict__ bsums) {
    int g = blockIdx.x * 256 + threadIdx.x;
    if (g < N_NODES) data[g] += bsums[blockIdx.x];
    if (g == 0) data[N_NODES] = N_EDGES;
}

__global__ __launch_bounds__(256) void fill_kernel(const int* __restrict__ src,
                                                   const int* __restrict__ dst,
                                                   int* __restrict__ cursor,
                                                   int* __restrict__ srcs) {
    int e = blockIdx.x * 256 + threadIdx.x;
    if (e < N_EDGES) {
        int p = atomicAdd(&cursor[dst[e]], 1);
        srcs[p] = src[e];
    }
}

// ---------------- aggregation (bf16 in, bf16 out, fp32 accum) ----------------

__global__ __launch_bounds__(256) void aggregate_bf16(const unsigned short* __restrict__ xb,
                                                      const int* __restrict__ row_start,
                                                      const int* __restrict__ srcs,
                                                      unsigned short* __restrict__ aggb) {
    int wave = threadIdx.x >> 6;
    int lane = threadIdx.x & 63;
    int node = blockIdx.x * 4 + wave;
    if (node >= N_NODES) return;
    int beg = row_start[node];
    int end = row_start[node + 1];
    const unsigned int* xw = (const unsigned int*)xb;
    float ax = 0.f, ay = 0.f;
    int j = beg;
    for (; j + 1 < end; j += 2) {
        unsigned int u0 = xw[(size_t)srcs[j] * 64 + lane];
        unsigned int u1 = xw[(size_t)srcs[j + 1] * 64 + lane];
        ax += bfl(u0) + bfl(u1);
        ay += bfh(u0) + bfh(u1);
    }
    if (j < end) {
        unsigned int u = xw[(size_t)srcs[j] * 64 + lane];
        ax += bfl(u);
        ay += bfh(u);
    }
    unsigned int o = ((unsigned)f2bf(ay) << 16) | f2bf(ax);
    ((unsigned int*)aggb)[(size_t)node * 64 + lane] = o;
}

// ---------------- GEMM: out = [aggb|xb] @ Wt_l^T + b  (bf16 MFMA) ----------------
// BM=128, BN=128, K=256 in 4 steps of 64. 4 waves, each 64x64 (4x4 frags 16x16).
// LDS rows padded to 72 bf16 (144B stride -> even bank-group spread on ds_read_b128).

#define LDP 72

__global__ __launch_bounds__(256) void gemm_bf16(const unsigned short* __restrict__ aggb,
                                                 const unsigned short* __restrict__ xb,
                                                 const unsigned short* __restrict__ Wt_l,
                                                 const float* __restrict__ bias,
                                                 unsigned short* __restrict__ outb,
                                                 float* __restrict__ outf) {
    __shared__ unsigned short As[128 * LDP];
    __shared__ unsigned short Bs[128 * LDP];

    int tid = threadIdx.x;
    int lane = tid & 63;
    int wave = tid >> 6;
    int wm = wave >> 1;      // 0..1
    int wn = wave & 1;       // 0..1
    int row0 = blockIdx.x * 128;

    f32x4 acc[4][4];
#pragma unroll
    for (int m = 0; m < 4; ++m)
#pragma unroll
        for (int n = 0; n < 4; ++n) acc[m][n] = (f32x4){0.f, 0.f, 0.f, 0.f};

    for (int s = 0; s < 4; ++s) {
        const unsigned short* Asrc = (s < 2) ? aggb : xb;
        int k0 = (s & 1) * 64;

        // stage A: 128 rows x 64 bf16 (1024 x 16B)
#pragma unroll
        for (int i = 0; i < 4; ++i) {
            int c = tid + i * 256;
            int r = c >> 3, sg = c & 7;
            int gr = row0 + r;
            uint4 v = {0u, 0u, 0u, 0u};
            if (gr < N_NODES) v = *(const uint4*)(Asrc + (size_t)gr * DIM + k0 + sg * 8);
            *(uint4*)&As[r * LDP + sg * 8] = v;
        }
        // stage B (Wt is [col][256])
#pragma unroll
        for (int i = 0; i < 4; ++i) {
            int c = tid + i * 256;
            int col = c >> 3, sg = c & 7;
            *(uint4*)&Bs[col * LDP + sg * 8] =
                *(const uint4*)(Wt_l + (size_t)col * 256 + s * 64 + sg * 8);
        }
        __syncthreads();

#pragma unroll
        for (int kk = 0; kk < 64; kk += 32) {
            short8 a[4], b[4];
#pragma unroll
            for (int m = 0; m < 4; ++m)
                a[m] = *(const short8*)&As[(wm * 64 + m * 16 + (lane & 15)) * LDP + kk + (lane >> 4) * 8];
#pragma unroll
            for (int n = 0; n < 4; ++n)
                b[n] = *(const short8*)&Bs[(wn * 64 + n * 16 + (lane & 15)) * LDP + kk + (lane >> 4) * 8];
#pragma unroll
            for (int m = 0; m < 4; ++m)
#pragma unroll
                for (int n = 0; n < 4; ++n)
                    acc[m][n] = __builtin_amdgcn_mfma_f32_16x16x32_bf16(a[m], b[n], acc[m][n], 0, 0, 0);
        }
        __syncthreads();
    }

    // epilogue: + bias; write bf16 (mid layers) or fp32 (final)
#pragma unroll
    for (int n = 0; n < 4; ++n) {
        int col = wn * 64 + n * 16 + (lane & 15);
        float bv = bias[col];
#pragma unroll
        for (int m = 0; m < 4; ++m) {
            int rbase = row0 + wm * 64 + m * 16 + (lane >> 4) * 4;
#pragma unroll
            for (int r = 0; r < 4; ++r) {
                int row = rbase + r;
                if (row < N_NODES) {
                    float v = acc[m][n][r] + bv;
                    if (outf) outf[(size_t)row * DIM + col] = v;
                    else      outb[(size_t)row * DIM + col] = f2bf(v);
                }
            }
        }
    }
}

// ---------------- launch ----------------

extern "C" void kernel_launch(void* const* d_in, const int* in_sizes, int n_in,
                              void* d_out, int out_size, void* d_ws, size_t ws_size,
                              hipStream_t stream) {
    const float* x0    = (const float*)d_in[0];
    const int*   ei    = (const int*)d_in[1];
    const float* Wrel  = (const float*)d_in[2];
    const float* Wroot = (const float*)d_in[3];
    const float* bvec  = (const float*)d_in[4];
    float* out = (float*)d_out;

    char* ws = (char*)d_ws;
    const size_t XB = (size_t)N_NODES * DIM * sizeof(unsigned short);  // 12.8 MB
    unsigned short* xbA  = (unsigned short*)ws;
    unsigned short* xbB  = (unsigned short*)(ws + XB);
    unsigned short* aggb = (unsigned short*)(ws + 2 * XB);
    unsigned short* Wt   = (unsigned short*)(ws + 3 * XB);             // 196608 B
    int* row_start = (int*)(ws + 3 * XB + 196608);
    int* cursor    = row_start + 50176;
    int* srcs      = cursor + 50176;
    int* bsums     = srcs + N_EDGES;

    const int* src = ei;
    const int* dst = ei + N_EDGES;

    convert_x<<<(N_NODES * DIM / 8 + 255) / 256, 256, 0, stream>>>(x0, xbA);
    prep_w<<<(LAYERS * 2 * 128 * 32 + 255) / 256, 256, 0, stream>>>(Wrel, Wroot, Wt);

    hipMemsetAsync(row_start, 0, (N_NODES + 1) * sizeof(int), stream);
    hist_kernel<<<(N_EDGES + 255) / 256, 256, 0, stream>>>(dst, row_start);
    scan_a<<<SCAN_BLOCKS, 256, 0, stream>>>(row_start, bsums);
    scan_b<<<1, 256, 0, stream>>>(bsums);
    scan_c<<<SCAN_BLOCKS, 256, 0, stream>>>(row_start, bsums);
    hipMemcpyAsync(cursor, row_start, N_NODES * sizeof(int),
                   hipMemcpyDeviceToDevice, stream);
    fill_kernel<<<(N_EDGES + 255) / 256, 256, 0, stream>>>(src, dst, cursor, srcs);

    unsigned short* xin = xbA;
    unsigned short* xouts[LAYERS] = {xbB, xbA, nullptr};
    for (int l = 0; l < LAYERS; ++l) {
        aggregate_bf16<<<(N_NODES + 3) / 4, 256, 0, stream>>>(xin, row_start, srcs, aggb);
        gemm_bf16<<<(N_NODES + 127) / 128, 256, 0, stream>>>(
            aggb, xin, Wt + (size_t)l * 128 * 256, bvec + (size_t)l * DIM,
            xouts[l], (l == LAYERS - 1) ? out : nullptr);
        xin = xouts[l];
    }
}

// Round 3
// 325.236 us; speedup vs baseline: 1.6460x; 1.1804x over previous
//
#include <hip/hip_runtime.h>

#define N_NODES 50000
#define N_EDGES 800000
#define DIM     128
#define LAYERS  3

#define SCAN_BLOCKS ((N_NODES + 255) / 256)   // 196

using short8 = __attribute__((ext_vector_type(8))) short;
using f32x4  = __attribute__((ext_vector_type(4))) float;

__device__ __forceinline__ unsigned short f2bf(float f) {
    unsigned int u = __builtin_bit_cast(unsigned int, f);
    unsigned int r = (u + 0x7fffu + ((u >> 16) & 1u)) >> 16;   // RTN-even
    return (unsigned short)r;
}
__device__ __forceinline__ float bfl(unsigned int u) {   // low 16 bits = bf16
    return __builtin_bit_cast(float, u << 16);
}
__device__ __forceinline__ float bfh(unsigned int u) {   // high 16 bits = bf16
    return __builtin_bit_cast(float, u & 0xffff0000u);
}

// ---------------- one-time converts ----------------

__global__ __launch_bounds__(256) void convert_x(const float* __restrict__ x,
                                                 unsigned short* __restrict__ xb) {
    int t = blockIdx.x * 256 + threadIdx.x;
    size_t base = (size_t)t * 8;
    if (base >= (size_t)N_NODES * DIM) return;
    float4 v0 = *(const float4*)(x + base);
    float4 v1 = *(const float4*)(x + base + 4);
    uint4 o;
    o.x = ((unsigned)f2bf(v0.y) << 16) | f2bf(v0.x);
    o.y = ((unsigned)f2bf(v0.w) << 16) | f2bf(v0.z);
    o.z = ((unsigned)f2bf(v1.y) << 16) | f2bf(v1.x);
    o.w = ((unsigned)f2bf(v1.w) << 16) | f2bf(v1.z);
    *(uint4*)(xb + base) = o;
}

// W_rel/W_root fp32 [l][k][col] -> Wt bf16 [l][col][256] (k<128: rel, k>=128: root)
__global__ __launch_bounds__(256) void prep_w(const float* __restrict__ Wrel,
                                              const float* __restrict__ Wroot,
                                              unsigned short* __restrict__ Wt) {
    int t = blockIdx.x * 256 + threadIdx.x;   // 3*2*128*32 = 24576 threads
    if (t >= LAYERS * 2 * 128 * 32) return;
    int k4  = t & 31;
    int col = (t >> 5) & 127;
    int mat = (t >> 12) & 1;
    int l   = t >> 13;
    const float* W = (mat ? Wroot : Wrel) + (size_t)l * DIM * DIM;
    int k0 = k4 * 4;
    unsigned short b0 = f2bf(W[(size_t)(k0 + 0) * DIM + col]);
    unsigned short b1 = f2bf(W[(size_t)(k0 + 1) * DIM + col]);
    unsigned short b2 = f2bf(W[(size_t)(k0 + 2) * DIM + col]);
    unsigned short b3 = f2bf(W[(size_t)(k0 + 3) * DIM + col]);
    uint2 o;
    o.x = ((unsigned)b1 << 16) | b0;
    o.y = ((unsigned)b3 << 16) | b2;
    *(uint2*)(Wt + (size_t)l * 128 * 256 + (size_t)col * 256 + mat * 128 + k0) = o;
}

// ---------------- CSR build ----------------

__global__ __launch_bounds__(256) void hist_kernel(const int* __restrict__ dst,
                                                   int* __restrict__ counts) {
    int e = blockIdx.x * 256 + threadIdx.x;
    if (e < N_EDGES) atomicAdd(&counts[dst[e]], 1);
}

__global__ __launch_bounds__(256) void scan_a(int* __restrict__ data,
                                              int* __restrict__ bsums) {
    __shared__ int sh[256];
    int tid = threadIdx.x;
    int g = blockIdx.x * 256 + tid;
    int v = (g < N_NODES) ? data[g] : 0;
    sh[tid] = v;
    __syncthreads();
    for (int off = 1; off < 256; off <<= 1) {
        int t = (tid >= off) ? sh[tid - off] : 0;
        __syncthreads();
        sh[tid] += t;
        __syncthreads();
    }
    int incl = sh[tid];
    if (g < N_NODES) data[g] = incl - v;
    if (tid == 255) bsums[blockIdx.x] = incl;
}

__global__ __launch_bounds__(256) void scan_b(int* __restrict__ bsums) {
    __shared__ int sh[256];
    int tid = threadIdx.x;
    int v = (tid < SCAN_BLOCKS) ? bsums[tid] : 0;
    sh[tid] = v;
    __syncthreads();
    for (int off = 1; off < 256; off <<= 1) {
        int t = (tid >= off) ? sh[tid - off] : 0;
        __syncthreads();
        sh[tid] += t;
        __syncthreads();
    }
    if (tid < SCAN_BLOCKS) bsums[tid] = sh[tid] - v;
}

__global__ __launch_bounds__(256) void scan_c(int* __restrict__ data,
                                              const int* __restrict__ bsums) {
    int g = blockIdx.x * 256 + threadIdx.x;
    if (g < N_NODES) data[g] += bsums[blockIdx.x];
    if (g == 0) data[N_NODES] = N_EDGES;
}

__global__ __launch_bounds__(256) void fill_kernel(const int* __restrict__ src,
                                                   const int* __restrict__ dst,
                                                   int* __restrict__ cursor,
                                                   int* __restrict__ srcs) {
    int e = blockIdx.x * 256 + threadIdx.x;
    if (e < N_EDGES) {
        int p = atomicAdd(&cursor[dst[e]], 1);
        srcs[p] = src[e];
    }
}

// ---------------- aggregation ----------------
// 16-lane group owns one node; lane L holds 16B (8 bf16) slice of the row.
// 4 nodes/wave, 16 nodes/block. Unroll 4 -> 4 KB in flight per wave.

__device__ __forceinline__ void acc8(float* a, uint4 v) {
    a[0] += bfl(v.x); a[1] += bfh(v.x);
    a[2] += bfl(v.y); a[3] += bfh(v.y);
    a[4] += bfl(v.z); a[5] += bfh(v.z);
    a[6] += bfl(v.w); a[7] += bfh(v.w);
}

__global__ __launch_bounds__(256) void aggregate_bf16(const unsigned short* __restrict__ xb,
                                                      const int* __restrict__ row_start,
                                                      const int* __restrict__ srcs,
                                                      unsigned short* __restrict__ aggb) {
    int tid  = threadIdx.x;
    int L    = tid & 15;          // lane in group
    int node = blockIdx.x * 16 + (tid >> 4);
    if (node >= N_NODES) return;
    int beg = row_start[node];
    int end = row_start[node + 1];

    const uint4* xq = (const uint4*)xb;   // one row = 16 uint4
    float a[8] = {0.f, 0.f, 0.f, 0.f, 0.f, 0.f, 0.f, 0.f};

    int j = beg;
    for (; j + 3 < end; j += 4) {
        uint4 v0 = xq[(size_t)srcs[j]     * 16 + L];
        uint4 v1 = xq[(size_t)srcs[j + 1] * 16 + L];
        uint4 v2 = xq[(size_t)srcs[j + 2] * 16 + L];
        uint4 v3 = xq[(size_t)srcs[j + 3] * 16 + L];
        acc8(a, v0); acc8(a, v1); acc8(a, v2); acc8(a, v3);
    }
    for (; j < end; ++j) {
        uint4 v = xq[(size_t)srcs[j] * 16 + L];
        acc8(a, v);
    }

    uint4 o;
    o.x = ((unsigned)f2bf(a[1]) << 16) | f2bf(a[0]);
    o.y = ((unsigned)f2bf(a[3]) << 16) | f2bf(a[2]);
    o.z = ((unsigned)f2bf(a[5]) << 16) | f2bf(a[4]);
    o.w = ((unsigned)f2bf(a[7]) << 16) | f2bf(a[6]);
    ((uint4*)aggb)[(size_t)node * 16 + L] = o;
}

// ---------------- GEMM: out = [aggb|xb] @ Wt_l^T + b  (bf16 MFMA) ----------------
// BM=128, BN=128, K=256 in 4 steps of 64. 4 waves, each 64x64 (4x4 frags 16x16).

#define LDP 72

__global__ __launch_bounds__(256) void gemm_bf16(const unsigned short* __restrict__ aggb,
                                                 const unsigned short* __restrict__ xb,
                                                 const unsigned short* __restrict__ Wt_l,
                                                 const float* __restrict__ bias,
                                                 unsigned short* __restrict__ outb,
                                                 float* __restrict__ outf) {
    __shared__ unsigned short As[128 * LDP];
    __shared__ unsigned short Bs[128 * LDP];

    int tid = threadIdx.x;
    int lane = tid & 63;
    int wave = tid >> 6;
    int wm = wave >> 1;      // 0..1
    int wn = wave & 1;       // 0..1
    int row0 = blockIdx.x * 128;

    f32x4 acc[4][4];
#pragma unroll
    for (int m = 0; m < 4; ++m)
#pragma unroll
        for (int n = 0; n < 4; ++n) acc[m][n] = (f32x4){0.f, 0.f, 0.f, 0.f};

    for (int s = 0; s < 4; ++s) {
        const unsigned short* Asrc = (s < 2) ? aggb : xb;
        int k0 = (s & 1) * 64;

#pragma unroll
        for (int i = 0; i < 4; ++i) {
            int c = tid + i * 256;
            int r = c >> 3, sg = c & 7;
            int gr = row0 + r;
            uint4 v = {0u, 0u, 0u, 0u};
            if (gr < N_NODES) v = *(const uint4*)(Asrc + (size_t)gr * DIM + k0 + sg * 8);
            *(uint4*)&As[r * LDP + sg * 8] = v;
        }
#pragma unroll
        for (int i = 0; i < 4; ++i) {
            int c = tid + i * 256;
            int col = c >> 3, sg = c & 7;
            *(uint4*)&Bs[col * LDP + sg * 8] =
                *(const uint4*)(Wt_l + (size_t)col * 256 + s * 64 + sg * 8);
        }
        __syncthreads();

#pragma unroll
        for (int kk = 0; kk < 64; kk += 32) {
            short8 a[4], b[4];
#pragma unroll
            for (int m = 0; m < 4; ++m)
                a[m] = *(const short8*)&As[(wm * 64 + m * 16 + (lane & 15)) * LDP + kk + (lane >> 4) * 8];
#pragma unroll
            for (int n = 0; n < 4; ++n)
                b[n] = *(const short8*)&Bs[(wn * 64 + n * 16 + (lane & 15)) * LDP + kk + (lane >> 4) * 8];
#pragma unroll
            for (int m = 0; m < 4; ++m)
#pragma unroll
                for (int n = 0; n < 4; ++n)
                    acc[m][n] = __builtin_amdgcn_mfma_f32_16x16x32_bf16(a[m], b[n], acc[m][n], 0, 0, 0);
        }
        __syncthreads();
    }

#pragma unroll
    for (int n = 0; n < 4; ++n) {
        int col = wn * 64 + n * 16 + (lane & 15);
        float bv = bias[col];
#pragma unroll
        for (int m = 0; m < 4; ++m) {
            int rbase = row0 + wm * 64 + m * 16 + (lane >> 4) * 4;
#pragma unroll
            for (int r = 0; r < 4; ++r) {
                int row = rbase + r;
                if (row < N_NODES) {
                    float v = acc[m][n][r] + bv;
                    if (outf) outf[(size_t)row * DIM + col] = v;
                    else      outb[(size_t)row * DIM + col] = f2bf(v);
                }
            }
        }
    }
}

// ---------------- launch ----------------

extern "C" void kernel_launch(void* const* d_in, const int* in_sizes, int n_in,
                              void* d_out, int out_size, void* d_ws, size_t ws_size,
                              hipStream_t stream) {
    const float* x0    = (const float*)d_in[0];
    const int*   ei    = (const int*)d_in[1];
    const float* Wrel  = (const float*)d_in[2];
    const float* Wroot = (const float*)d_in[3];
    const float* bvec  = (const float*)d_in[4];
    float* out = (float*)d_out;

    char* ws = (char*)d_ws;
    const size_t XB = (size_t)N_NODES * DIM * sizeof(unsigned short);  // 12.8 MB
    unsigned short* xbA  = (unsigned short*)ws;
    unsigned short* xbB  = (unsigned short*)(ws + XB);
    unsigned short* aggb = (unsigned short*)(ws + 2 * XB);
    unsigned short* Wt   = (unsigned short*)(ws + 3 * XB);             // 196608 B
    int* row_start = (int*)(ws + 3 * XB + 196608);
    int* cursor    = row_start + 50176;
    int* srcs      = cursor + 50176;
    int* bsums     = srcs + N_EDGES;

    const int* src = ei;
    const int* dst = ei + N_EDGES;

    convert_x<<<(N_NODES * DIM / 8 + 255) / 256, 256, 0, stream>>>(x0, xbA);
    prep_w<<<(LAYERS * 2 * 128 * 32 + 255) / 256, 256, 0, stream>>>(Wrel, Wroot, Wt);

    hipMemsetAsync(row_start, 0, (N_NODES + 1) * sizeof(int), stream);
    hist_kernel<<<(N_EDGES + 255) / 256, 256, 0, stream>>>(dst, row_start);
    scan_a<<<SCAN_BLOCKS, 256, 0, stream>>>(row_start, bsums);
    scan_b<<<1, 256, 0, stream>>>(bsums);
    scan_c<<<SCAN_BLOCKS, 256, 0, stream>>>(row_start, bsums);
    hipMemcpyAsync(cursor, row_start, N_NODES * sizeof(int),
                   hipMemcpyDeviceToDevice, stream);
    fill_kernel<<<(N_EDGES + 255) / 256, 256, 0, stream>>>(src, dst, cursor, srcs);

    unsigned short* xin = xbA;
    unsigned short* xouts[LAYERS] = {xbB, xbA, nullptr};
    for (int l = 0; l < LAYERS; ++l) {
        aggregate_bf16<<<(N_NODES + 15) / 16, 256, 0, stream>>>(xin, row_start, srcs, aggb);
        gemm_bf16<<<(N_NODES + 127) / 128, 256, 0, stream>>>(
            aggb, xin, Wt + (size_t)l * 128 * 256, bvec + (size_t)l * DIM,
            xouts[l], (l == LAYERS - 1) ? out : nullptr);
        xin = xouts[l];
    }
}

// Round 5
// 260.068 us; speedup vs baseline: 2.0585x; 1.2506x over previous
//
#include <hip/hip_runtime.h>

#define N_NODES 50000
#define N_EDGES 800000
#define DIM     128
#define LAYERS  3

#define BSHIFT    7
#define N_BUCKETS 391                  // ceil(50000/128)
#define CHUNK     16384
#define N_CHUNKS  49                   // ceil(800000/16384)

using short8 = __attribute__((ext_vector_type(8))) short;
using f32x4  = __attribute__((ext_vector_type(4))) float;

__device__ __forceinline__ unsigned short f2bf(float f) {
    unsigned int u = __builtin_bit_cast(unsigned int, f);
    unsigned int r = (u + 0x7fffu + ((u >> 16) & 1u)) >> 16;   // RTN-even
    return (unsigned short)r;
}
__device__ __forceinline__ float bfl(unsigned int u) {
    return __builtin_bit_cast(float, u << 16);
}
__device__ __forceinline__ float bfh(unsigned int u) {
    return __builtin_bit_cast(float, u & 0xffff0000u);
}

// ---------------- one-time converts ----------------

__global__ __launch_bounds__(256) void convert_x(const float* __restrict__ x,
                                                 unsigned short* __restrict__ xb) {
    int t = blockIdx.x * 256 + threadIdx.x;
    size_t base = (size_t)t * 8;
    if (base >= (size_t)N_NODES * DIM) return;
    float4 v0 = *(const float4*)(x + base);
    float4 v1 = *(const float4*)(x + base + 4);
    uint4 o;
    o.x = ((unsigned)f2bf(v0.y) << 16) | f2bf(v0.x);
    o.y = ((unsigned)f2bf(v0.w) << 16) | f2bf(v0.z);
    o.z = ((unsigned)f2bf(v1.y) << 16) | f2bf(v1.x);
    o.w = ((unsigned)f2bf(v1.w) << 16) | f2bf(v1.z);
    *(uint4*)(xb + base) = o;
}

// W_rel/W_root fp32 [l][k][col] -> Wt bf16 [l][col][256] (k<128: rel, k>=128: root)
__global__ __launch_bounds__(256) void prep_w(const float* __restrict__ Wrel,
                                              const float* __restrict__ Wroot,
                                              unsigned short* __restrict__ Wt) {
    int t = blockIdx.x * 256 + threadIdx.x;
    if (t >= LAYERS * 2 * 128 * 32) return;
    int k4  = t & 31;
    int col = (t >> 5) & 127;
    int mat = (t >> 12) & 1;
    int l   = t >> 13;
    const float* W = (mat ? Wroot : Wrel) + (size_t)l * DIM * DIM;
    int k0 = k4 * 4;
    unsigned short b0 = f2bf(W[(size_t)(k0 + 0) * DIM + col]);
    unsigned short b1 = f2bf(W[(size_t)(k0 + 1) * DIM + col]);
    unsigned short b2 = f2bf(W[(size_t)(k0 + 2) * DIM + col]);
    unsigned short b3 = f2bf(W[(size_t)(k0 + 3) * DIM + col]);
    uint2 o;
    o.x = ((unsigned)b1 << 16) | b0;
    o.y = ((unsigned)b3 << 16) | b2;
    *(uint2*)(Wt + (size_t)l * 128 * 256 + (size_t)col * 256 + mat * 128 + k0) = o;
}

// ---------------- binned CSR build (all global writes coalesced) ----------------

// per-chunk LDS histogram over 391 buckets
__global__ __launch_bounds__(1024) void bin_count(const int* __restrict__ dst,
                                                  int* __restrict__ bcnt) {
    __shared__ int hist[N_BUCKETS];
    int tid = threadIdx.x, chunk = blockIdx.x;
    for (int t = tid; t < N_BUCKETS; t += 1024) hist[t] = 0;
    __syncthreads();
    int base = chunk * CHUNK;
    for (int i = 0; i < CHUNK; i += 1024) {
        int e = base + i + tid;
        if (e < N_EDGES) atomicAdd(&hist[dst[e] >> BSHIFT], 1);
    }
    __syncthreads();
    for (int t = tid; t < N_BUCKETS; t += 1024)
        bcnt[t * N_CHUNKS + chunk] = hist[t];
}

// per-bucket exclusive scan over chunks (49 values)
__global__ __launch_bounds__(64) void bscan_a(const int* __restrict__ bcnt,
                                              int* __restrict__ boff,
                                              int* __restrict__ btot) {
    __shared__ int sh[64];
    int b = blockIdx.x, j = threadIdx.x;
    int v = (j < N_CHUNKS) ? bcnt[b * N_CHUNKS + j] : 0;
    sh[j] = v;
    __syncthreads();
    for (int off = 1; off < 64; off <<= 1) {
        int t = (j >= off) ? sh[j - off] : 0;
        __syncthreads();
        sh[j] += t;
        __syncthreads();
    }
    if (j < N_CHUNKS) boff[b * N_CHUNKS + j] = sh[j] - v;
    if (j == 63) btot[b] = sh[63];
}

// exclusive scan of bucket totals (391 values, one block)
__global__ __launch_bounds__(512) void bscan_b(const int* __restrict__ btot,
                                               int* __restrict__ bucket_start) {
    __shared__ int sh[512];
    int j = threadIdx.x;
    int v = (j < N_BUCKETS) ? btot[j] : 0;
    sh[j] = v;
    __syncthreads();
    for (int off = 1; off < 512; off <<= 1) {
        int t = (j >= off) ? sh[j - off] : 0;
        __syncthreads();
        sh[j] += t;
        __syncthreads();
    }
    if (j < N_BUCKETS) bucket_start[j] = sh[j] - v;
    if (j == N_BUCKETS - 1) bucket_start[N_BUCKETS] = sh[j];   // == N_EDGES
}

// scatter edges into contiguous per-bucket runs (LDS cursors; writes cluster)
__global__ __launch_bounds__(1024) void bin_scatter(const int* __restrict__ src,
                                                    const int* __restrict__ dst,
                                                    const int* __restrict__ bucket_start,
                                                    const int* __restrict__ boff,
                                                    unsigned int* __restrict__ pairs) {
    __shared__ int cur[N_BUCKETS];
    int tid = threadIdx.x, chunk = blockIdx.x;
    for (int t = tid; t < N_BUCKETS; t += 1024)
        cur[t] = bucket_start[t] + boff[t * N_CHUNKS + chunk];
    __syncthreads();
    int base = chunk * CHUNK;
    for (int i = 0; i < CHUNK; i += 1024) {
        int e = base + i + tid;
        if (e < N_EDGES) {
            int d = dst[e];
            int b = d >> BSHIFT;
            int p = atomicAdd(&cur[b], 1);
            pairs[p] = ((unsigned)(d & 127) << 16) | (unsigned)src[e];
        }
    }
}

// final in-LDS counting sort per bucket -> CSR (srcs as ushort, all coalesced)
__global__ __launch_bounds__(1024) void fill_lds(const unsigned int* __restrict__ pairs,
                                                 const int* __restrict__ bucket_start,
                                                 int* __restrict__ row_start,
                                                 unsigned short* __restrict__ srcs16) {
    __shared__ int hist[128];
    __shared__ int offs[128];
    __shared__ int cur[128];
    __shared__ unsigned short srt[4096];
    int b = blockIdx.x, tid = threadIdx.x;
    int s0 = bucket_start[b], s1 = bucket_start[b + 1];
    int cnt = s1 - s0;
    if (tid < 128) hist[tid] = 0;
    __syncthreads();
    for (int k = tid; k < cnt; k += 1024)
        atomicAdd(&hist[pairs[s0 + k] >> 16], 1);
    __syncthreads();
    if (tid < 128) offs[tid] = hist[tid];
    __syncthreads();
    for (int off = 1; off < 128; off <<= 1) {
        int t = 0;
        if (tid < 128 && tid >= off) t = offs[tid - off];
        __syncthreads();
        if (tid < 128) offs[tid] += t;
        __syncthreads();
    }
    if (tid < 128) {
        int excl = offs[tid] - hist[tid];   // exclusive scan
        cur[tid] = excl;
        int node = b * 128 + tid;
        if (node <= N_NODES) row_start[node] = s0 + excl;  // covers sentinel at 50000
    }
    __syncthreads();
    for (int k = tid; k < cnt; k += 1024) {
        unsigned int u = pairs[s0 + k];
        int p = atomicAdd(&cur[u >> 16], 1);
        srt[p] = (unsigned short)(u & 0xffffu);
    }
    __syncthreads();
    for (int k = tid; k < cnt; k += 1024)
        srcs16[s0 + k] = srt[k];
}

// ---------------- aggregation ----------------
// 16-lane group owns one node; lane L holds 16B (8 bf16) slice of the row.

__device__ __forceinline__ void acc8(float* a, uint4 v) {
    a[0] += bfl(v.x); a[1] += bfh(v.x);
    a[2] += bfl(v.y); a[3] += bfh(v.y);
    a[4] += bfl(v.z); a[5] += bfh(v.z);
    a[6] += bfl(v.w); a[7] += bfh(v.w);
}

__global__ __launch_bounds__(256) void aggregate_bf16(const unsigned short* __restrict__ xb,
                                                      const int* __restrict__ row_start,
                                                      const unsigned short* __restrict__ srcs,
                                                      unsigned short* __restrict__ aggb) {
    int tid  = threadIdx.x;
    int L    = tid & 15;
    int node = blockIdx.x * 16 + (tid >> 4);
    if (node >= N_NODES) return;
    int beg = row_start[node];
    int end = row_start[node + 1];

    const uint4* xq = (const uint4*)xb;   // one row = 16 uint4
    float a[8] = {0.f, 0.f, 0.f, 0.f, 0.f, 0.f, 0.f, 0.f};

    int j = beg;
    for (; j + 3 < end; j += 4) {
        uint4 v0 = xq[(size_t)srcs[j]     * 16 + L];
        uint4 v1 = xq[(size_t)srcs[j + 1] * 16 + L];
        uint4 v2 = xq[(size_t)srcs[j + 2] * 16 + L];
        uint4 v3 = xq[(size_t)srcs[j + 3] * 16 + L];
        acc8(a, v0); acc8(a, v1); acc8(a, v2); acc8(a, v3);
    }
    for (; j < end; ++j) {
        uint4 v = xq[(size_t)srcs[j] * 16 + L];
        acc8(a, v);
    }

    uint4 o;
    o.x = ((unsigned)f2bf(a[1]) << 16) | f2bf(a[0]);
    o.y = ((unsigned)f2bf(a[3]) << 16) | f2bf(a[2]);
    o.z = ((unsigned)f2bf(a[5]) << 16) | f2bf(a[4]);
    o.w = ((unsigned)f2bf(a[7]) << 16) | f2bf(a[6]);
    ((uint4*)aggb)[(size_t)node * 16 + L] = o;
}

// ---------------- GEMM: out = [aggb|xb] @ Wt_l^T + b  (bf16 MFMA) ----------------

#define LDP 72

__global__ __launch_bounds__(256) void gemm_bf16(const unsigned short* __restrict__ aggb,
                                                 const unsigned short* __restrict__ xb,
                                                 const unsigned short* __restrict__ Wt_l,
                                                 const float* __restrict__ bias,
                                                 unsigned short* __restrict__ outb,
                                                 float* __restrict__ outf) {
    __shared__ unsigned short As[128 * LDP];
    __shared__ unsigned short Bs[128 * LDP];

    int tid = threadIdx.x;
    int lane = tid & 63;
    int wave = tid >> 6;
    int wm = wave >> 1;
    int wn = wave & 1;
    int row0 = blockIdx.x * 128;

    f32x4 acc[4][4];
#pragma unroll
    for (int m = 0; m < 4; ++m)
#pragma unroll
        for (int n = 0; n < 4; ++n) acc[m][n] = (f32x4){0.f, 0.f, 0.f, 0.f};

    for (int s = 0; s < 4; ++s) {
        const unsigned short* Asrc = (s < 2) ? aggb : xb;
        int k0 = (s & 1) * 64;

#pragma unroll
        for (int i = 0; i < 4; ++i) {
            int c = tid + i * 256;
            int r = c >> 3, sg = c & 7;
            int gr = row0 + r;
            uint4 v = {0u, 0u, 0u, 0u};
            if (gr < N_NODES) v = *(const uint4*)(Asrc + (size_t)gr * DIM + k0 + sg * 8);
            *(uint4*)&As[r * LDP + sg * 8] = v;
        }
#pragma unroll
        for (int i = 0; i < 4; ++i) {
            int c = tid + i * 256;
            int col = c >> 3, sg = c & 7;
            *(uint4*)&Bs[col * LDP + sg * 8] =
                *(const uint4*)(Wt_l + (size_t)col * 256 + s * 64 + sg * 8);
        }
        __syncthreads();

#pragma unroll
        for (int kk = 0; kk < 64; kk += 32) {
            short8 a[4], b[4];
#pragma unroll
            for (int m = 0; m < 4; ++m)
                a[m] = *(const short8*)&As[(wm * 64 + m * 16 + (lane & 15)) * LDP + kk + (lane >> 4) * 8];
#pragma unroll
            for (int n = 0; n < 4; ++n)
                b[n] = *(const short8*)&Bs[(wn * 64 + n * 16 + (lane & 15)) * LDP + kk + (lane >> 4) * 8];
#pragma unroll
            for (int m = 0; m < 4; ++m)
#pragma unroll
                for (int n = 0; n < 4; ++n)
                    acc[m][n] = __builtin_amdgcn_mfma_f32_16x16x32_bf16(a[m], b[n], acc[m][n], 0, 0, 0);
        }
        __syncthreads();
    }

#pragma unroll
    for (int n = 0; n < 4; ++n) {
        int col = wn * 64 + n * 16 + (lane & 15);
        float bv = bias[col];
#pragma unroll
        for (int m = 0; m < 4; ++m) {
            int rbase = row0 + wm * 64 + m * 16 + (lane >> 4) * 4;
#pragma unroll
            for (int r = 0; r < 4; ++r) {
                int row = rbase + r;
                if (row < N_NODES) {
                    float v = acc[m][n][r] + bv;
                    if (outf) outf[(size_t)row * DIM + col] = v;
                    else      outb[(size_t)row * DIM + col] = f2bf(v);
                }
            }
        }
    }
}

// ---------------- launch ----------------

extern "C" void kernel_launch(void* const* d_in, const int* in_sizes, int n_in,
                              void* d_out, int out_size, void* d_ws, size_t ws_size,
                              hipStream_t stream) {
    const float* x0    = (const float*)d_in[0];
    const int*   ei    = (const int*)d_in[1];
    const float* Wrel  = (const float*)d_in[2];
    const float* Wroot = (const float*)d_in[3];
    const float* bvec  = (const float*)d_in[4];
    float* out = (float*)d_out;

    char* ws = (char*)d_ws;
    const size_t XB = (size_t)N_NODES * DIM * sizeof(unsigned short);  // 12,800,000
    unsigned short* xbA  = (unsigned short*)ws;
    unsigned short* xbB  = (unsigned short*)(ws + XB);
    unsigned short* aggb = (unsigned short*)(ws + 2 * XB);
    // build-time scratch overlaps aggb (dead before first aggregate)
    unsigned int* pairs  = (unsigned int*)(ws + 2 * XB);               // 3.2 MB
    int* bcnt            = (int*)(ws + 2 * XB + 3200000);              // 76,636 B
    int* boff            = (int*)(ws + 2 * XB + 3276800);              // 76,636 B
    int* btot            = (int*)(ws + 2 * XB + 3353600);              // 1,564 B
    int* bucket_start    = (int*)(ws + 2 * XB + 3355648);              // 1,568 B
    unsigned short* Wt   = (unsigned short*)(ws + 3 * XB);             // 196,608 B
    unsigned short* srcs16 = (unsigned short*)(ws + 3 * XB + 196608);  // 1.6 MB
    int* row_start       = (int*)(ws + 3 * XB + 196608 + 1600000);     // 200,004 B

    const int* src = ei;
    const int* dst = ei + N_EDGES;

    convert_x<<<(N_NODES * DIM / 8 + 255) / 256, 256, 0, stream>>>(x0, xbA);
    prep_w<<<(LAYERS * 2 * 128 * 32 + 255) / 256, 256, 0, stream>>>(Wrel, Wroot, Wt);

    bin_count<<<N_CHUNKS, 1024, 0, stream>>>(dst, bcnt);
    bscan_a<<<N_BUCKETS, 64, 0, stream>>>(bcnt, boff, btot);
    bscan_b<<<1, 512, 0, stream>>>(btot, bucket_start);
    bin_scatter<<<N_CHUNKS, 1024, 0, stream>>>(src, dst, bucket_start, boff, pairs);
    fill_lds<<<N_BUCKETS, 1024, 0, stream>>>(pairs, bucket_start, row_start, srcs16);

    unsigned short* xin = xbA;
    unsigned short* xouts[LAYERS] = {xbB, xbA, nullptr};
    for (int l = 0; l < LAYERS; ++l) {
        aggregate_bf16<<<(N_NODES + 15) / 16, 256, 0, stream>>>(xin, row_start, srcs16, aggb);
        gemm_bf16<<<(N_NODES + 127) / 128, 256, 0, stream>>>(
            aggb, xin, Wt + (size_t)l * 128 * 256, bvec + (size_t)l * DIM,
            xouts[l], (l == LAYERS - 1) ? out : nullptr);
        xin = xouts[l];
    }
}

// Round 8
// 255.707 us; speedup vs baseline: 2.0936x; 1.0171x over previous
//
#include <hip/hip_runtime.h>

#define N_NODES 50000
#define N_EDGES 800000
#define DIM     128
#define LAYERS  3

#define BSHIFT    7
#define N_BUCKETS 391                  // ceil(50000/128)
#define CHUNK     16384
#define N_CHUNKS  49                   // ceil(800000/16384)

using short8 = __attribute__((ext_vector_type(8))) short;
using f32x4  = __attribute__((ext_vector_type(4))) float;

__device__ __forceinline__ unsigned short f2bf(float f) {
    unsigned int u = __builtin_bit_cast(unsigned int, f);
    unsigned int r = (u + 0x7fffu + ((u >> 16) & 1u)) >> 16;   // RTN-even
    return (unsigned short)r;
}
__device__ __forceinline__ float bfl(unsigned int u) {
    return __builtin_bit_cast(float, u << 16);
}
__device__ __forceinline__ float bfh(unsigned int u) {
    return __builtin_bit_cast(float, u & 0xffff0000u);
}

// ---------------- one-time converts ----------------

__global__ __launch_bounds__(256) void convert_x(const float* __restrict__ x,
                                                 unsigned short* __restrict__ xb) {
    int t = blockIdx.x * 256 + threadIdx.x;
    size_t base = (size_t)t * 8;
    if (base >= (size_t)N_NODES * DIM) return;
    float4 v0 = *(const float4*)(x + base);
    float4 v1 = *(const float4*)(x + base + 4);
    uint4 o;
    o.x = ((unsigned)f2bf(v0.y) << 16) | f2bf(v0.x);
    o.y = ((unsigned)f2bf(v0.w) << 16) | f2bf(v0.z);
    o.z = ((unsigned)f2bf(v1.y) << 16) | f2bf(v1.x);
    o.w = ((unsigned)f2bf(v1.w) << 16) | f2bf(v1.z);
    *(uint4*)(xb + base) = o;
}

// W_rel/W_root fp32 [l][k][col] -> Wt bf16 [l][col][256] (k<128: rel, k>=128: root)
__global__ __launch_bounds__(256) void prep_w(const float* __restrict__ Wrel,
                                              const float* __restrict__ Wroot,
                                              unsigned short* __restrict__ Wt) {
    int t = blockIdx.x * 256 + threadIdx.x;
    if (t >= LAYERS * 2 * 128 * 32) return;
    int k4  = t & 31;
    int col = (t >> 5) & 127;
    int mat = (t >> 12) & 1;
    int l   = t >> 13;
    const float* W = (mat ? Wroot : Wrel) + (size_t)l * DIM * DIM;
    int k0 = k4 * 4;
    unsigned short b0 = f2bf(W[(size_t)(k0 + 0) * DIM + col]);
    unsigned short b1 = f2bf(W[(size_t)(k0 + 1) * DIM + col]);
    unsigned short b2 = f2bf(W[(size_t)(k0 + 2) * DIM + col]);
    unsigned short b3 = f2bf(W[(size_t)(k0 + 3) * DIM + col]);
    uint2 o;
    o.x = ((unsigned)b1 << 16) | b0;
    o.y = ((unsigned)b3 << 16) | b2;
    *(uint2*)(Wt + (size_t)l * 128 * 256 + (size_t)col * 256 + mat * 128 + k0) = o;
}

// ---------------- binned CSR build (all global writes coalesced) ----------------

__global__ __launch_bounds__(1024) void bin_count(const int* __restrict__ dst,
                                                  int* __restrict__ bcnt) {
    __shared__ int hist[N_BUCKETS];
    int tid = threadIdx.x, chunk = blockIdx.x;
    for (int t = tid; t < N_BUCKETS; t += 1024) hist[t] = 0;
    __syncthreads();
    int base = chunk * CHUNK;
    for (int i = 0; i < CHUNK; i += 1024) {
        int e = base + i + tid;
        if (e < N_EDGES) atomicAdd(&hist[dst[e] >> BSHIFT], 1);
    }
    __syncthreads();
    for (int t = tid; t < N_BUCKETS; t += 1024)
        bcnt[t * N_CHUNKS + chunk] = hist[t];
}

__global__ __launch_bounds__(64) void bscan_a(const int* __restrict__ bcnt,
                                              int* __restrict__ boff,
                                              int* __restrict__ btot) {
    __shared__ int sh[64];
    int b = blockIdx.x, j = threadIdx.x;
    int v = (j < N_CHUNKS) ? bcnt[b * N_CHUNKS + j] : 0;
    sh[j] = v;
    __syncthreads();
    for (int off = 1; off < 64; off <<= 1) {
        int t = (j >= off) ? sh[j - off] : 0;
        __syncthreads();
        sh[j] += t;
        __syncthreads();
    }
    if (j < N_CHUNKS) boff[b * N_CHUNKS + j] = sh[j] - v;
    if (j == 63) btot[b] = sh[63];
}

__global__ __launch_bounds__(512) void bscan_b(const int* __restrict__ btot,
                                               int* __restrict__ bucket_start) {
    __shared__ int sh[512];
    int j = threadIdx.x;
    int v = (j < N_BUCKETS) ? btot[j] : 0;
    sh[j] = v;
    __syncthreads();
    for (int off = 1; off < 512; off <<= 1) {
        int t = (j >= off) ? sh[j - off] : 0;
        __syncthreads();
        sh[j] += t;
        __syncthreads();
    }
    if (j < N_BUCKETS) bucket_start[j] = sh[j] - v;
    if (j == N_BUCKETS - 1) bucket_start[N_BUCKETS] = sh[j];   // == N_EDGES
}

__global__ __launch_bounds__(1024) void bin_scatter(const int* __restrict__ src,
                                                    const int* __restrict__ dst,
                                                    const int* __restrict__ bucket_start,
                                                    const int* __restrict__ boff,
                                                    unsigned int* __restrict__ pairs) {
    __shared__ int cur[N_BUCKETS];
    int tid = threadIdx.x, chunk = blockIdx.x;
    for (int t = tid; t < N_BUCKETS; t += 1024)
        cur[t] = bucket_start[t] + boff[t * N_CHUNKS + chunk];
    __syncthreads();
    int base = chunk * CHUNK;
    for (int i = 0; i < CHUNK; i += 1024) {
        int e = base + i + tid;
        if (e < N_EDGES) {
            int d = dst[e];
            int b = d >> BSHIFT;
            int p = atomicAdd(&cur[b], 1);
            pairs[p] = ((unsigned)(d & 127) << 16) | (unsigned)src[e];
        }
    }
}

__global__ __launch_bounds__(1024) void fill_lds(const unsigned int* __restrict__ pairs,
                                                 const int* __restrict__ bucket_start,
                                                 int* __restrict__ row_start,
                                                 unsigned short* __restrict__ srcs16) {
    __shared__ int hist[128];
    __shared__ int offs[128];
    __shared__ int cur[128];
    __shared__ unsigned short srt[4096];
    int b = blockIdx.x, tid = threadIdx.x;
    int s0 = bucket_start[b], s1 = bucket_start[b + 1];
    int cnt = s1 - s0;
    if (tid < 128) hist[tid] = 0;
    __syncthreads();
    for (int k = tid; k < cnt; k += 1024)
        atomicAdd(&hist[pairs[s0 + k] >> 16], 1);
    __syncthreads();
    if (tid < 128) offs[tid] = hist[tid];
    __syncthreads();
    for (int off = 1; off < 128; off <<= 1) {
        int t = 0;
        if (tid < 128 && tid >= off) t = offs[tid - off];
        __syncthreads();
        if (tid < 128) offs[tid] += t;
        __syncthreads();
    }
    if (tid < 128) {
        int excl = offs[tid] - hist[tid];   // exclusive scan
        cur[tid] = excl;
        int node = b * 128 + tid;
        if (node <= N_NODES) row_start[node] = s0 + excl;  // covers sentinel at 50000
    }
    __syncthreads();
    for (int k = tid; k < cnt; k += 1024) {
        unsigned int u = pairs[s0 + k];
        int p = atomicAdd(&cur[u >> 16], 1);
        srt[p] = (unsigned short)(u & 0xffffu);
    }
    __syncthreads();
    for (int k = tid; k < cnt; k += 1024)
        srcs16[s0 + k] = srt[k];
}

// ---------------- aggregation ----------------
// 16-lane group owns one node; lane L holds 16B (8 bf16) slice of the row.

__device__ __forceinline__ void acc8(float* a, uint4 v) {
    a[0] += bfl(v.x); a[1] += bfh(v.x);
    a[2] += bfl(v.y); a[3] += bfh(v.y);
    a[4] += bfl(v.z); a[5] += bfh(v.z);
    a[6] += bfl(v.w); a[7] += bfh(v.w);
}

__global__ __launch_bounds__(256) void aggregate_bf16(const unsigned short* __restrict__ xb,
                                                      const int* __restrict__ row_start,
                                                      const unsigned short* __restrict__ srcs,
                                                      unsigned short* __restrict__ aggb) {
    int tid  = threadIdx.x;
    int L    = tid & 15;
    int node = blockIdx.x * 16 + (tid >> 4);
    if (node >= N_NODES) return;
    int beg = row_start[node];
    int end = row_start[node + 1];

    const uint4* xq = (const uint4*)xb;   // one row = 16 uint4
    float a[8] = {0.f, 0.f, 0.f, 0.f, 0.f, 0.f, 0.f, 0.f};

    int j = beg;
    for (; j + 3 < end; j += 4) {
        uint4 v0 = xq[(size_t)srcs[j]     * 16 + L];
        uint4 v1 = xq[(size_t)srcs[j + 1] * 16 + L];
        uint4 v2 = xq[(size_t)srcs[j + 2] * 16 + L];
        uint4 v3 = xq[(size_t)srcs[j + 3] * 16 + L];
        acc8(a, v0); acc8(a, v1); acc8(a, v2); acc8(a, v3);
    }
    for (; j < end; ++j) {
        uint4 v = xq[(size_t)srcs[j] * 16 + L];
        acc8(a, v);
    }

    uint4 o;
    o.x = ((unsigned)f2bf(a[1]) << 16) | f2bf(a[0]);
    o.y = ((unsigned)f2bf(a[3]) << 16) | f2bf(a[2]);
    o.z = ((unsigned)f2bf(a[5]) << 16) | f2bf(a[4]);
    o.w = ((unsigned)f2bf(a[7]) << 16) | f2bf(a[6]);
    ((uint4*)aggb)[(size_t)node * 16 + L] = o;
}

// ---------------- GEMM: out = [aggb|xb] @ Wt_l^T + b  (bf16 MFMA) ----------------
// Barrier-free main loop:
//   * A-fragments loaded DIRECTLY from global (row-major aggb/xb): lane reads
//     16B at row (l&15), ks (l>>4)*8 -> 16 full 64B lines per frag, L2-hot.
//   * B (64 KB layer weights) staged ONCE into LDS with 16B-granule XOR
//     swizzle (q ^= col&7) -> ~2-way reads (free); one barrier total.
//   * BUGFIX vs r6: a column is 32 uint4 granules (256 bf16), so the staging
//     split is col = c>>5, q = c&31 (was >>4/&15 -> LDS overflow -> NaN).
// 4 waves, each: 32 rows x 128 cols (acc 2x8 f32x4). Grid 391, 2 blocks/CU.

__global__ __launch_bounds__(256) void gemm_bf16(const unsigned short* __restrict__ aggb,
                                                 const unsigned short* __restrict__ xb,
                                                 const unsigned short* __restrict__ Wt_l,
                                                 const float* __restrict__ bias,
                                                 unsigned short* __restrict__ outb,
                                                 float* __restrict__ outf) {
    __shared__ unsigned short Bs[128 * 256];   // 64 KB, swizzled 16B granules

    int tid  = threadIdx.x;
    int lane = tid & 63;
    int w    = tid >> 6;

    // stage all weights once: 4096 uint4, 16 per thread
#pragma unroll
    for (int i = 0; i < 16; ++i) {
        int c   = tid + i * 256;      // uint4 index
        int col = c >> 5;             // 32 uint4 per column
        int q   = c & 31;
        uint4 v = ((const uint4*)Wt_l)[c];
        *(uint4*)&Bs[col * 256 + 8 * (q ^ (col & 7))] = v;
    }
    __syncthreads();

    int row0 = blockIdx.x * 128 + w * 32;

    f32x4 acc[2][8];
#pragma unroll
    for (int m = 0; m < 2; ++m)
#pragma unroll
        for (int n = 0; n < 8; ++n) acc[m][n] = (f32x4){0.f, 0.f, 0.f, 0.f};

    const short8 zero8 = {0, 0, 0, 0, 0, 0, 0, 0};

#pragma unroll
    for (int ch = 0; ch < 8; ++ch) {
        const unsigned short* Asrc = (ch < 4) ? aggb : xb;
        int k0 = (ch & 3) * 32 + (lane >> 4) * 8;

        short8 a[2];
#pragma unroll
        for (int m = 0; m < 2; ++m) {
            int r = row0 + m * 16 + (lane & 15);
            a[m] = (r < N_NODES) ? *(const short8*)(Asrc + (size_t)r * DIM + k0) : zero8;
        }

        int qbase = ch * 4 + (lane >> 4);   // granule 0..31 of concat-K
#pragma unroll
        for (int n = 0; n < 8; ++n) {
            int col = n * 16 + (lane & 15);
            short8 b = *(const short8*)&Bs[col * 256 + 8 * (qbase ^ (col & 7))];
            acc[0][n] = __builtin_amdgcn_mfma_f32_16x16x32_bf16(a[0], b, acc[0][n], 0, 0, 0);
            acc[1][n] = __builtin_amdgcn_mfma_f32_16x16x32_bf16(a[1], b, acc[1][n], 0, 0, 0);
        }
    }

    // epilogue: + bias; write bf16 (mid layers) or fp32 (final)
#pragma unroll
    for (int n = 0; n < 8; ++n) {
        int col = n * 16 + (lane & 15);
        float bv = bias[col];
#pragma unroll
        for (int m = 0; m < 2; ++m) {
            int rb = row0 + m * 16 + (lane >> 4) * 4;
#pragma unroll
            for (int r = 0; r < 4; ++r) {
                int row = rb + r;
                if (row < N_NODES) {
                    float v = acc[m][n][r] + bv;
                    if (outf) outf[(size_t)row * DIM + col] = v;
                    else      outb[(size_t)row * DIM + col] = f2bf(v);
                }
            }
        }
    }
}

// ---------------- launch ----------------

extern "C" void kernel_launch(void* const* d_in, const int* in_sizes, int n_in,
                              void* d_out, int out_size, void* d_ws, size_t ws_size,
                              hipStream_t stream) {
    const float* x0    = (const float*)d_in[0];
    const int*   ei    = (const int*)d_in[1];
    const float* Wrel  = (const float*)d_in[2];
    const float* Wroot = (const float*)d_in[3];
    const float* bvec  = (const float*)d_in[4];
    float* out = (float*)d_out;

    char* ws = (char*)d_ws;
    const size_t XB = (size_t)N_NODES * DIM * sizeof(unsigned short);  // 12,800,000
    unsigned short* xbA  = (unsigned short*)ws;
    unsigned short* xbB  = (unsigned short*)(ws + XB);
    unsigned short* aggb = (unsigned short*)(ws + 2 * XB);
    // build-time scratch overlaps aggb (dead before first aggregate)
    unsigned int* pairs  = (unsigned int*)(ws + 2 * XB);               // 3.2 MB
    int* bcnt            = (int*)(ws + 2 * XB + 3200000);              // 76,636 B
    int* boff            = (int*)(ws + 2 * XB + 3276800);              // 76,636 B
    int* btot            = (int*)(ws + 2 * XB + 3353600);              // 1,564 B
    int* bucket_start    = (int*)(ws + 2 * XB + 3355648);              // 1,568 B
    unsigned short* Wt   = (unsigned short*)(ws + 3 * XB);             // 196,608 B
    unsigned short* srcs16 = (unsigned short*)(ws + 3 * XB + 196608);  // 1.6 MB
    int* row_start       = (int*)(ws + 3 * XB + 196608 + 1600000);     // 200,004 B

    const int* src = ei;
    const int* dst = ei + N_EDGES;

    convert_x<<<(N_NODES * DIM / 8 + 255) / 256, 256, 0, stream>>>(x0, xbA);
    prep_w<<<(LAYERS * 2 * 128 * 32 + 255) / 256, 256, 0, stream>>>(Wrel, Wroot, Wt);

    bin_count<<<N_CHUNKS, 1024, 0, stream>>>(dst, bcnt);
    bscan_a<<<N_BUCKETS, 64, 0, stream>>>(bcnt, boff, btot);
    bscan_b<<<1, 512, 0, stream>>>(btot, bucket_start);
    bin_scatter<<<N_CHUNKS, 1024, 0, stream>>>(src, dst, bucket_start, boff, pairs);
    fill_lds<<<N_BUCKETS, 1024, 0, stream>>>(pairs, bucket_start, row_start, srcs16);

    unsigned short* xin = xbA;
    unsigned short* xouts[LAYERS] = {xbB, xbA, nullptr};
    for (int l = 0; l < LAYERS; ++l) {
        aggregate_bf16<<<(N_NODES + 15) / 16, 256, 0, stream>>>(xin, row_start, srcs16, aggb);
        gemm_bf16<<<(N_NODES + 127) / 128, 256, 0, stream>>>(
            aggb, xin, Wt + (size_t)l * 128 * 256, bvec + (size_t)l * DIM,
            xouts[l], (l == LAYERS - 1) ? out : nullptr);
        xin = xouts[l];
    }
}

// Round 9
// 243.616 us; speedup vs baseline: 2.1975x; 1.0496x over previous
//
#include <hip/hip_runtime.h>

#define N_NODES 50000
#define N_EDGES 800000
#define DIM     128
#define LAYERS  3

#define BSHIFT    7
#define N_BUCKETS 391                  // ceil(50000/128)
#define CHUNK     4096
#define N_CHUNKS  196                  // ceil(800000/4096)

using short8 = __attribute__((ext_vector_type(8))) short;
using f32x4  = __attribute__((ext_vector_type(4))) float;

__device__ __forceinline__ unsigned short f2bf(float f) {
    unsigned int u = __builtin_bit_cast(unsigned int, f);
    unsigned int r = (u + 0x7fffu + ((u >> 16) & 1u)) >> 16;   // RTN-even
    return (unsigned short)r;
}
__device__ __forceinline__ float bfl(unsigned int u) {
    return __builtin_bit_cast(float, u << 16);
}
__device__ __forceinline__ float bfh(unsigned int u) {
    return __builtin_bit_cast(float, u & 0xffff0000u);
}

// ---------------- one-time converts ----------------

__global__ __launch_bounds__(256) void convert_x(const float* __restrict__ x,
                                                 unsigned short* __restrict__ xb) {
    int t = blockIdx.x * 256 + threadIdx.x;
    size_t base = (size_t)t * 8;
    if (base >= (size_t)N_NODES * DIM) return;
    float4 v0 = *(const float4*)(x + base);
    float4 v1 = *(const float4*)(x + base + 4);
    uint4 o;
    o.x = ((unsigned)f2bf(v0.y) << 16) | f2bf(v0.x);
    o.y = ((unsigned)f2bf(v0.w) << 16) | f2bf(v0.z);
    o.z = ((unsigned)f2bf(v1.y) << 16) | f2bf(v1.x);
    o.w = ((unsigned)f2bf(v1.w) << 16) | f2bf(v1.z);
    *(uint4*)(xb + base) = o;
}

// W_rel/W_root fp32 [l][k][col] -> Wt bf16 [l][col][256] (k<128: rel, k>=128: root)
__global__ __launch_bounds__(256) void prep_w(const float* __restrict__ Wrel,
                                              const float* __restrict__ Wroot,
                                              unsigned short* __restrict__ Wt) {
    int t = blockIdx.x * 256 + threadIdx.x;
    if (t >= LAYERS * 2 * 128 * 32) return;
    int k4  = t & 31;
    int col = (t >> 5) & 127;
    int mat = (t >> 12) & 1;
    int l   = t >> 13;
    const float* W = (mat ? Wroot : Wrel) + (size_t)l * DIM * DIM;
    int k0 = k4 * 4;
    unsigned short b0 = f2bf(W[(size_t)(k0 + 0) * DIM + col]);
    unsigned short b1 = f2bf(W[(size_t)(k0 + 1) * DIM + col]);
    unsigned short b2 = f2bf(W[(size_t)(k0 + 2) * DIM + col]);
    unsigned short b3 = f2bf(W[(size_t)(k0 + 3) * DIM + col]);
    uint2 o;
    o.x = ((unsigned)b1 << 16) | b0;
    o.y = ((unsigned)b3 << 16) | b2;
    *(uint2*)(Wt + (size_t)l * 128 * 256 + (size_t)col * 256 + mat * 128 + k0) = o;
}

// ---------------- binned CSR build (all global writes coalesced) ----------------
// bcnt/boff layout: [chunk][bucket] so scan + scatter reads are coalesced.

__global__ __launch_bounds__(1024) void bin_count(const int* __restrict__ dst,
                                                  int* __restrict__ bcnt) {
    __shared__ int hist[N_BUCKETS];
    int tid = threadIdx.x, chunk = blockIdx.x;
    for (int t = tid; t < N_BUCKETS; t += 1024) hist[t] = 0;
    __syncthreads();
    int base = chunk * CHUNK;
#pragma unroll
    for (int i = 0; i < CHUNK; i += 1024) {
        int e = base + i + tid;
        if (e < N_EDGES) atomicAdd(&hist[dst[e] >> BSHIFT], 1);
    }
    __syncthreads();
    for (int t = tid; t < N_BUCKETS; t += 1024)
        bcnt[chunk * N_BUCKETS + t] = hist[t];
}

// merged 2D scan, one block: per-bucket running sum over chunks -> boff,
// then block-exclusive scan of bucket totals -> bucket_start.
__global__ __launch_bounds__(512) void bscan(const int* __restrict__ bcnt,
                                             int* __restrict__ boff,
                                             int* __restrict__ bucket_start) {
    __shared__ int sh[512];
    int b = threadIdx.x;
    int run = 0;
    if (b < N_BUCKETS) {
        for (int c = 0; c < N_CHUNKS; ++c) {
            int v = bcnt[c * N_BUCKETS + b];
            boff[c * N_BUCKETS + b] = run;
            run += v;
        }
    }
    sh[b] = (b < N_BUCKETS) ? run : 0;
    __syncthreads();
    for (int off = 1; off < 512; off <<= 1) {
        int t = (b >= off) ? sh[b - off] : 0;
        __syncthreads();
        sh[b] += t;
        __syncthreads();
    }
    if (b < N_BUCKETS) bucket_start[b] = sh[b] - run;
    if (b == N_BUCKETS - 1) bucket_start[N_BUCKETS] = sh[b];   // == N_EDGES
}

__global__ __launch_bounds__(1024) void bin_scatter(const int* __restrict__ src,
                                                    const int* __restrict__ dst,
                                                    const int* __restrict__ bucket_start,
                                                    const int* __restrict__ boff,
                                                    unsigned int* __restrict__ pairs) {
    __shared__ int cur[N_BUCKETS];
    int tid = threadIdx.x, chunk = blockIdx.x;
    for (int t = tid; t < N_BUCKETS; t += 1024)
        cur[t] = bucket_start[t] + boff[chunk * N_BUCKETS + t];
    __syncthreads();
    int base = chunk * CHUNK;
#pragma unroll
    for (int i = 0; i < CHUNK; i += 1024) {
        int e = base + i + tid;
        if (e < N_EDGES) {
            int d = dst[e];
            int b = d >> BSHIFT;
            int p = atomicAdd(&cur[b], 1);
            pairs[p] = ((unsigned)(d & 127) << 16) | (unsigned)src[e];
        }
    }
}

__global__ __launch_bounds__(1024) void fill_lds(const unsigned int* __restrict__ pairs,
                                                 const int* __restrict__ bucket_start,
                                                 int* __restrict__ row_start,
                                                 unsigned short* __restrict__ srcs16) {
    __shared__ int hist[128];
    __shared__ int offs[128];
    __shared__ int cur[128];
    __shared__ unsigned short srt[4096];
    int b = blockIdx.x, tid = threadIdx.x;
    int s0 = bucket_start[b], s1 = bucket_start[b + 1];
    int cnt = s1 - s0;
    if (tid < 128) hist[tid] = 0;
    __syncthreads();
    for (int k = tid; k < cnt; k += 1024)
        atomicAdd(&hist[pairs[s0 + k] >> 16], 1);
    __syncthreads();
    if (tid < 128) offs[tid] = hist[tid];
    __syncthreads();
    for (int off = 1; off < 128; off <<= 1) {
        int t = 0;
        if (tid < 128 && tid >= off) t = offs[tid - off];
        __syncthreads();
        if (tid < 128) offs[tid] += t;
        __syncthreads();
    }
    if (tid < 128) {
        int excl = offs[tid] - hist[tid];   // exclusive scan
        cur[tid] = excl;
        int node = b * 128 + tid;
        if (node <= N_NODES) row_start[node] = s0 + excl;  // covers sentinel at 50000
    }
    __syncthreads();
    for (int k = tid; k < cnt; k += 1024) {
        unsigned int u = pairs[s0 + k];
        int p = atomicAdd(&cur[u >> 16], 1);
        srt[p] = (unsigned short)(u & 0xffffu);
    }
    __syncthreads();
    for (int k = tid; k < cnt; k += 1024)
        srcs16[s0 + k] = srt[k];
}

// ---------------- aggregation ----------------
// 16-lane group owns one node; lane L holds 16B (8 bf16) slice of the row.
// Latency-chain minimization: unroll-8 main, unroll-4 tier, then a
// predicated clamp-index batch for the <=3 remainder (loads issue together).

__device__ __forceinline__ void acc8(float* a, uint4 v) {
    a[0] += bfl(v.x); a[1] += bfh(v.x);
    a[2] += bfl(v.y); a[3] += bfh(v.y);
    a[4] += bfl(v.z); a[5] += bfh(v.z);
    a[6] += bfl(v.w); a[7] += bfh(v.w);
}

__global__ __launch_bounds__(256) void aggregate_bf16(const unsigned short* __restrict__ xb,
                                                      const int* __restrict__ row_start,
                                                      const unsigned short* __restrict__ srcs,
                                                      unsigned short* __restrict__ aggb) {
    int tid  = threadIdx.x;
    int L    = tid & 15;
    int node = blockIdx.x * 16 + (tid >> 4);
    if (node >= N_NODES) return;
    int j   = row_start[node];
    int end = row_start[node + 1];

    const uint4* xq = (const uint4*)xb;   // one row = 16 uint4
    float a[8] = {0.f, 0.f, 0.f, 0.f, 0.f, 0.f, 0.f, 0.f};

    for (; j + 7 < end; j += 8) {
        uint4 v0 = xq[(size_t)srcs[j]     * 16 + L];
        uint4 v1 = xq[(size_t)srcs[j + 1] * 16 + L];
        uint4 v2 = xq[(size_t)srcs[j + 2] * 16 + L];
        uint4 v3 = xq[(size_t)srcs[j + 3] * 16 + L];
        uint4 v4 = xq[(size_t)srcs[j + 4] * 16 + L];
        uint4 v5 = xq[(size_t)srcs[j + 5] * 16 + L];
        uint4 v6 = xq[(size_t)srcs[j + 6] * 16 + L];
        uint4 v7 = xq[(size_t)srcs[j + 7] * 16 + L];
        acc8(a, v0); acc8(a, v1); acc8(a, v2); acc8(a, v3);
        acc8(a, v4); acc8(a, v5); acc8(a, v6); acc8(a, v7);
    }
    if (j + 3 < end) {
        uint4 v0 = xq[(size_t)srcs[j]     * 16 + L];
        uint4 v1 = xq[(size_t)srcs[j + 1] * 16 + L];
        uint4 v2 = xq[(size_t)srcs[j + 2] * 16 + L];
        uint4 v3 = xq[(size_t)srcs[j + 3] * 16 + L];
        acc8(a, v0); acc8(a, v1); acc8(a, v2); acc8(a, v3);
        j += 4;
    }
    int rem = end - j;                      // 0..3
    if (rem > 0) {
        int j1 = (rem > 1) ? j + 1 : j;     // clamped: loads issue in parallel
        int j2 = (rem > 2) ? j + 2 : j;
        uint4 v0 = xq[(size_t)srcs[j]  * 16 + L];
        uint4 v1 = xq[(size_t)srcs[j1] * 16 + L];
        uint4 v2 = xq[(size_t)srcs[j2] * 16 + L];
        acc8(a, v0);
        if (rem > 1) acc8(a, v1);
        if (rem > 2) acc8(a, v2);
    }

    uint4 o;
    o.x = ((unsigned)f2bf(a[1]) << 16) | f2bf(a[0]);
    o.y = ((unsigned)f2bf(a[3]) << 16) | f2bf(a[2]);
    o.z = ((unsigned)f2bf(a[5]) << 16) | f2bf(a[4]);
    o.w = ((unsigned)f2bf(a[7]) << 16) | f2bf(a[6]);
    ((uint4*)aggb)[(size_t)node * 16 + L] = o;
}

// ---------------- GEMM: out = [aggb|xb] @ Wt_l^T + b  (bf16 MFMA) ----------------
// Barrier-free main loop; A direct from global (L2-hot), B staged once with
// 16B-granule XOR swizzle. 4 waves x (32 rows x 128 cols). Unchanged from r8.

__global__ __launch_bounds__(256) void gemm_bf16(const unsigned short* __restrict__ aggb,
                                                 const unsigned short* __restrict__ xb,
                                                 const unsigned short* __restrict__ Wt_l,
                                                 const float* __restrict__ bias,
                                                 unsigned short* __restrict__ outb,
                                                 float* __restrict__ outf) {
    __shared__ unsigned short Bs[128 * 256];   // 64 KB, swizzled 16B granules

    int tid  = threadIdx.x;
    int lane = tid & 63;
    int w    = tid >> 6;

    // stage all weights once: 4096 uint4, 16 per thread
#pragma unroll
    for (int i = 0; i < 16; ++i) {
        int c   = tid + i * 256;      // uint4 index
        int col = c >> 5;             // 32 uint4 per column
        int q   = c & 31;
        uint4 v = ((const uint4*)Wt_l)[c];
        *(uint4*)&Bs[col * 256 + 8 * (q ^ (col & 7))] = v;
    }
    __syncthreads();

    int row0 = blockIdx.x * 128 + w * 32;

    f32x4 acc[2][8];
#pragma unroll
    for (int m = 0; m < 2; ++m)
#pragma unroll
        for (int n = 0; n < 8; ++n) acc[m][n] = (f32x4){0.f, 0.f, 0.f, 0.f};

    const short8 zero8 = {0, 0, 0, 0, 0, 0, 0, 0};

#pragma unroll
    for (int ch = 0; ch < 8; ++ch) {
        const unsigned short* Asrc = (ch < 4) ? aggb : xb;
        int k0 = (ch & 3) * 32 + (lane >> 4) * 8;

        short8 a[2];
#pragma unroll
        for (int m = 0; m < 2; ++m) {
            int r = row0 + m * 16 + (lane & 15);
            a[m] = (r < N_NODES) ? *(const short8*)(Asrc + (size_t)r * DIM + k0) : zero8;
        }

        int qbase = ch * 4 + (lane >> 4);   // granule 0..31 of concat-K
#pragma unroll
        for (int n = 0; n < 8; ++n) {
            int col = n * 16 + (lane & 15);
            short8 b = *(const short8*)&Bs[col * 256 + 8 * (qbase ^ (col & 7))];
            acc[0][n] = __builtin_amdgcn_mfma_f32_16x16x32_bf16(a[0], b, acc[0][n], 0, 0, 0);
            acc[1][n] = __builtin_amdgcn_mfma_f32_16x16x32_bf16(a[1], b, acc[1][n], 0, 0, 0);
        }
    }

    // epilogue: + bias; write bf16 (mid layers) or fp32 (final)
#pragma unroll
    for (int n = 0; n < 8; ++n) {
        int col = n * 16 + (lane & 15);
        float bv = bias[col];
#pragma unroll
        for (int m = 0; m < 2; ++m) {
            int rb = row0 + m * 16 + (lane >> 4) * 4;
#pragma unroll
            for (int r = 0; r < 4; ++r) {
                int row = rb + r;
                if (row < N_NODES) {
                    float v = acc[m][n][r] + bv;
                    if (outf) outf[(size_t)row * DIM + col] = v;
                    else      outb[(size_t)row * DIM + col] = f2bf(v);
                }
            }
        }
    }
}

// ---------------- launch ----------------

extern "C" void kernel_launch(void* const* d_in, const int* in_sizes, int n_in,
                              void* d_out, int out_size, void* d_ws, size_t ws_size,
                              hipStream_t stream) {
    const float* x0    = (const float*)d_in[0];
    const int*   ei    = (const int*)d_in[1];
    const float* Wrel  = (const float*)d_in[2];
    const float* Wroot = (const float*)d_in[3];
    const float* bvec  = (const float*)d_in[4];
    float* out = (float*)d_out;

    char* ws = (char*)d_ws;
    const size_t XB = (size_t)N_NODES * DIM * sizeof(unsigned short);  // 12,800,000
    unsigned short* xbA  = (unsigned short*)ws;
    unsigned short* xbB  = (unsigned short*)(ws + XB);
    unsigned short* aggb = (unsigned short*)(ws + 2 * XB);
    // build-time scratch overlaps aggb (dead before first aggregate)
    unsigned int* pairs  = (unsigned int*)(ws + 2 * XB);               // 3.2 MB
    int* bcnt            = (int*)(ws + 2 * XB + 3200000);              // 306,544 B
    int* boff            = (int*)(ws + 2 * XB + 3506944);              // 306,544 B
    int* bucket_start    = (int*)(ws + 2 * XB + 3813504);              // 1,568 B
    unsigned short* Wt   = (unsigned short*)(ws + 3 * XB);             // 196,608 B
    unsigned short* srcs16 = (unsigned short*)(ws + 3 * XB + 196608);  // 1.6 MB
    int* row_start       = (int*)(ws + 3 * XB + 196608 + 1600000);     // 200,004 B

    const int* src = ei;
    const int* dst = ei + N_EDGES;

    convert_x<<<(N_NODES * DIM / 8 + 255) / 256, 256, 0, stream>>>(x0, xbA);
    prep_w<<<(LAYERS * 2 * 128 * 32 + 255) / 256, 256, 0, stream>>>(Wrel, Wroot, Wt);

    bin_count<<<N_CHUNKS, 1024, 0, stream>>>(dst, bcnt);
    bscan<<<1, 512, 0, stream>>>(bcnt, boff, bucket_start);
    bin_scatter<<<N_CHUNKS, 1024, 0, stream>>>(src, dst, bucket_start, boff, pairs);
    fill_lds<<<N_BUCKETS, 1024, 0, stream>>>(pairs, bucket_start, row_start, srcs16);

    unsigned short* xin = xbA;
    unsigned short* xouts[LAYERS] = {xbB, xbA, nullptr};
    for (int l = 0; l < LAYERS; ++l) {
        aggregate_bf16<<<(N_NODES + 15) / 16, 256, 0, stream>>>(xin, row_start, srcs16, aggb);
        gemm_bf16<<<(N_NODES + 127) / 128, 256, 0, stream>>>(
            aggb, xin, Wt + (size_t)l * 128 * 256, bvec + (size_t)l * DIM,
            xouts[l], (l == LAYERS - 1) ? out : nullptr);
        xin = xouts[l];
    }
}

// Round 10
// 240.388 us; speedup vs baseline: 2.2270x; 1.0134x over previous
//
#include <hip/hip_runtime.h>

#define N_NODES 50000
#define N_EDGES 800000
#define DIM     128
#define LAYERS  3

#define BSHIFT    7
#define N_BUCKETS 391                  // ceil(50000/128)
#define CHUNK     4096
#define N_CHUNKS  196                  // ceil(800000/4096)

#define AS_STRIDE 136                  // shorts per LDS row (128 + 8 pad)

using short8 = __attribute__((ext_vector_type(8))) short;
using f32x4  = __attribute__((ext_vector_type(4))) float;

__device__ __forceinline__ unsigned short f2bf(float f) {
    unsigned int u = __builtin_bit_cast(unsigned int, f);
    unsigned int r = (u + 0x7fffu + ((u >> 16) & 1u)) >> 16;   // RTN-even
    return (unsigned short)r;
}
__device__ __forceinline__ float bfl(unsigned int u) {
    return __builtin_bit_cast(float, u << 16);
}
__device__ __forceinline__ float bfh(unsigned int u) {
    return __builtin_bit_cast(float, u & 0xffff0000u);
}

// ---------------- one-time converts ----------------

__global__ __launch_bounds__(256) void convert_x(const float* __restrict__ x,
                                                 unsigned short* __restrict__ xb) {
    int t = blockIdx.x * 256 + threadIdx.x;
    size_t base = (size_t)t * 8;
    if (base >= (size_t)N_NODES * DIM) return;
    float4 v0 = *(const float4*)(x + base);
    float4 v1 = *(const float4*)(x + base + 4);
    uint4 o;
    o.x = ((unsigned)f2bf(v0.y) << 16) | f2bf(v0.x);
    o.y = ((unsigned)f2bf(v0.w) << 16) | f2bf(v0.z);
    o.z = ((unsigned)f2bf(v1.y) << 16) | f2bf(v1.x);
    o.w = ((unsigned)f2bf(v1.w) << 16) | f2bf(v1.z);
    *(uint4*)(xb + base) = o;
}

// Weights -> fragment-major bf16: Wf[l][(ch*8+n)*64 + lane][8]
// frag (ch,n): col = n*16+(lane&15), concat-k = ch*32+(lane>>4)*8 .. +8
// concat-k < 128 -> W_rel[k][col], else W_root[k-128][col].
__global__ __launch_bounds__(256) void prep_wf(const float* __restrict__ Wrel,
                                               const float* __restrict__ Wroot,
                                               unsigned short* __restrict__ Wf) {
    int t = blockIdx.x * 256 + threadIdx.x;     // one uint4 (8 bf16) per thread
    if (t >= LAYERS * 4096) return;
    int l    = t >> 12;
    int rem  = t & 4095;
    int f    = rem >> 6;         // 0..63
    int lane = rem & 63;
    int ch = f >> 3, n = f & 7;
    int col = n * 16 + (lane & 15);
    int ck0 = ch * 32 + ((lane >> 4) << 3);
    const float* W = ((ck0 < 128) ? Wrel : Wroot) + (size_t)l * DIM * DIM;
    int k0 = ck0 & 127;
    unsigned short e[8];
#pragma unroll
    for (int i = 0; i < 8; ++i) e[i] = f2bf(W[(size_t)(k0 + i) * DIM + col]);
    uint4 o;
    o.x = ((unsigned)e[1] << 16) | e[0];
    o.y = ((unsigned)e[3] << 16) | e[2];
    o.z = ((unsigned)e[5] << 16) | e[4];
    o.w = ((unsigned)e[7] << 16) | e[6];
    *(uint4*)(Wf + (size_t)t * 8) = o;
}

// ---------------- binned CSR build (all global writes coalesced) ----------------
// bcnt/boff layout: [chunk][bucket] so scan + scatter reads are coalesced.

__global__ __launch_bounds__(1024) void bin_count(const int* __restrict__ dst,
                                                  int* __restrict__ bcnt) {
    __shared__ int hist[N_BUCKETS];
    int tid = threadIdx.x, chunk = blockIdx.x;
    for (int t = tid; t < N_BUCKETS; t += 1024) hist[t] = 0;
    __syncthreads();
    int base = chunk * CHUNK;
#pragma unroll
    for (int i = 0; i < CHUNK; i += 1024) {
        int e = base + i + tid;
        if (e < N_EDGES) atomicAdd(&hist[dst[e] >> BSHIFT], 1);
    }
    __syncthreads();
    for (int t = tid; t < N_BUCKETS; t += 1024)
        bcnt[chunk * N_BUCKETS + t] = hist[t];
}

// merged 2D scan, one block
__global__ __launch_bounds__(512) void bscan(const int* __restrict__ bcnt,
                                             int* __restrict__ boff,
                                             int* __restrict__ bucket_start) {
    __shared__ int sh[512];
    int b = threadIdx.x;
    int run = 0;
    if (b < N_BUCKETS) {
        for (int c = 0; c < N_CHUNKS; ++c) {
            int v = bcnt[c * N_BUCKETS + b];
            boff[c * N_BUCKETS + b] = run;
            run += v;
        }
    }
    sh[b] = (b < N_BUCKETS) ? run : 0;
    __syncthreads();
    for (int off = 1; off < 512; off <<= 1) {
        int t = (b >= off) ? sh[b - off] : 0;
        __syncthreads();
        sh[b] += t;
        __syncthreads();
    }
    if (b < N_BUCKETS) bucket_start[b] = sh[b] - run;
    if (b == N_BUCKETS - 1) bucket_start[N_BUCKETS] = sh[b];   // == N_EDGES
}

__global__ __launch_bounds__(1024) void bin_scatter(const int* __restrict__ src,
                                                    const int* __restrict__ dst,
                                                    const int* __restrict__ bucket_start,
                                                    const int* __restrict__ boff,
                                                    unsigned int* __restrict__ pairs) {
    __shared__ int cur[N_BUCKETS];
    int tid = threadIdx.x, chunk = blockIdx.x;
    for (int t = tid; t < N_BUCKETS; t += 1024)
        cur[t] = bucket_start[t] + boff[chunk * N_BUCKETS + t];
    __syncthreads();
    int base = chunk * CHUNK;
#pragma unroll
    for (int i = 0; i < CHUNK; i += 1024) {
        int e = base + i + tid;
        if (e < N_EDGES) {
            int d = dst[e];
            int b = d >> BSHIFT;
            int p = atomicAdd(&cur[b], 1);
            pairs[p] = ((unsigned)(d & 127) << 16) | (unsigned)src[e];
        }
    }
}

__global__ __launch_bounds__(1024) void fill_lds(const unsigned int* __restrict__ pairs,
                                                 const int* __restrict__ bucket_start,
                                                 int* __restrict__ row_start,
                                                 unsigned short* __restrict__ srcs16) {
    __shared__ int hist[128];
    __shared__ int offs[128];
    __shared__ int cur[128];
    __shared__ unsigned short srt[4096];
    int b = blockIdx.x, tid = threadIdx.x;
    int s0 = bucket_start[b], s1 = bucket_start[b + 1];
    int cnt = s1 - s0;
    if (tid < 128) hist[tid] = 0;
    __syncthreads();
    for (int k = tid; k < cnt; k += 1024)
        atomicAdd(&hist[pairs[s0 + k] >> 16], 1);
    __syncthreads();
    if (tid < 128) offs[tid] = hist[tid];
    __syncthreads();
    for (int off = 1; off < 128; off <<= 1) {
        int t = 0;
        if (tid < 128 && tid >= off) t = offs[tid - off];
        __syncthreads();
        if (tid < 128) offs[tid] += t;
        __syncthreads();
    }
    if (tid < 128) {
        int excl = offs[tid] - hist[tid];   // exclusive scan
        cur[tid] = excl;
        int node = b * 128 + tid;
        if (node <= N_NODES) row_start[node] = s0 + excl;  // covers sentinel at 50000
    }
    __syncthreads();
    for (int k = tid; k < cnt; k += 1024) {
        unsigned int u = pairs[s0 + k];
        int p = atomicAdd(&cur[u >> 16], 1);
        srt[p] = (unsigned short)(u & 0xffffu);
    }
    __syncthreads();
    for (int k = tid; k < cnt; k += 1024)
        srcs16[s0 + k] = srt[k];
}

// ---------------- fused layer: gather -> LDS -> MFMA GEMM ----------------
// Block = 64 output nodes, 256 threads.
// Phase 1: 16 groups x 4 nodes; lane L owns 16B slice; fp32 accum; bf16 to
//   As[64][AS_STRIDE] (pad 8 -> uniform bank slots on write and frag read).
// Phase 2: 4 waves x (16 rows x 128 cols). A-rel from LDS, A-root from
//   global xin (1 line/row), B frags from global Wf (coalesced 1KB, L2-hot).

__device__ __forceinline__ void acc8(float* a, uint4 v) {
    a[0] += bfl(v.x); a[1] += bfh(v.x);
    a[2] += bfl(v.y); a[3] += bfh(v.y);
    a[4] += bfl(v.z); a[5] += bfh(v.z);
    a[6] += bfl(v.w); a[7] += bfh(v.w);
}

__global__ __launch_bounds__(256) void layer_fused(const unsigned short* __restrict__ xin,
                                                   const int* __restrict__ row_start,
                                                   const unsigned short* __restrict__ srcs,
                                                   const unsigned short* __restrict__ Wf,
                                                   const float* __restrict__ bias,
                                                   unsigned short* __restrict__ outb,
                                                   float* __restrict__ outf) {
    __shared__ unsigned short As[64 * AS_STRIDE];   // 17,408 B

    int tid = threadIdx.x;
    const uint4* xq = (const uint4*)xin;

    // ---- phase 1: gather ----
    int L = tid & 15, grp = tid >> 4;
#pragma unroll
    for (int i = 0; i < 4; ++i) {
        int local = grp * 4 + i;
        int node = blockIdx.x * 64 + local;
        float a[8] = {0.f, 0.f, 0.f, 0.f, 0.f, 0.f, 0.f, 0.f};
        if (node < N_NODES) {
            int j = row_start[node], end = row_start[node + 1];
            for (; j + 7 < end; j += 8) {
                uint4 v0 = xq[(size_t)srcs[j]     * 16 + L];
                uint4 v1 = xq[(size_t)srcs[j + 1] * 16 + L];
                uint4 v2 = xq[(size_t)srcs[j + 2] * 16 + L];
                uint4 v3 = xq[(size_t)srcs[j + 3] * 16 + L];
                uint4 v4 = xq[(size_t)srcs[j + 4] * 16 + L];
                uint4 v5 = xq[(size_t)srcs[j + 5] * 16 + L];
                uint4 v6 = xq[(size_t)srcs[j + 6] * 16 + L];
                uint4 v7 = xq[(size_t)srcs[j + 7] * 16 + L];
                acc8(a, v0); acc8(a, v1); acc8(a, v2); acc8(a, v3);
                acc8(a, v4); acc8(a, v5); acc8(a, v6); acc8(a, v7);
            }
            if (j + 3 < end) {
                uint4 v0 = xq[(size_t)srcs[j]     * 16 + L];
                uint4 v1 = xq[(size_t)srcs[j + 1] * 16 + L];
                uint4 v2 = xq[(size_t)srcs[j + 2] * 16 + L];
                uint4 v3 = xq[(size_t)srcs[j + 3] * 16 + L];
                acc8(a, v0); acc8(a, v1); acc8(a, v2); acc8(a, v3);
                j += 4;
            }
            int rem = end - j;                      // 0..3
            if (rem > 0) {
                int j1 = (rem > 1) ? j + 1 : j;     // clamped: loads issue together
                int j2 = (rem > 2) ? j + 2 : j;
                uint4 v0 = xq[(size_t)srcs[j]  * 16 + L];
                uint4 v1 = xq[(size_t)srcs[j1] * 16 + L];
                uint4 v2 = xq[(size_t)srcs[j2] * 16 + L];
                acc8(a, v0);
                if (rem > 1) acc8(a, v1);
                if (rem > 2) acc8(a, v2);
            }
        }
        uint4 o;
        o.x = ((unsigned)f2bf(a[1]) << 16) | f2bf(a[0]);
        o.y = ((unsigned)f2bf(a[3]) << 16) | f2bf(a[2]);
        o.z = ((unsigned)f2bf(a[5]) << 16) | f2bf(a[4]);
        o.w = ((unsigned)f2bf(a[7]) << 16) | f2bf(a[6]);
        *(uint4*)&As[local * AS_STRIDE + L * 8] = o;
    }
    __syncthreads();

    // ---- phase 2: GEMM ----
    int lane = tid & 63, w = tid >> 6;
    int rloc = w * 16 + (lane & 15);

    f32x4 acc[8];
#pragma unroll
    for (int n = 0; n < 8; ++n) acc[n] = (f32x4){0.f, 0.f, 0.f, 0.f};

    const short8 zero8 = {0, 0, 0, 0, 0, 0, 0, 0};

#pragma unroll
    for (int ch = 0; ch < 8; ++ch) {
        short8 a;
        if (ch < 4) {
            a = *(const short8*)&As[rloc * AS_STRIDE + ch * 32 + (lane >> 4) * 8];
        } else {
            int r = blockIdx.x * 64 + rloc;
            int k0 = (ch - 4) * 32 + (lane >> 4) * 8;
            a = (r < N_NODES) ? *(const short8*)(xin + (size_t)r * DIM + k0) : zero8;
        }
#pragma unroll
        for (int n = 0; n < 8; ++n) {
            short8 b = *(const short8*)(Wf + ((size_t)(ch * 8 + n) * 64 + lane) * 8);
            acc[n] = __builtin_amdgcn_mfma_f32_16x16x32_bf16(a, b, acc[n], 0, 0, 0);
        }
    }

    // ---- epilogue ----
#pragma unroll
    for (int n = 0; n < 8; ++n) {
        int col = n * 16 + (lane & 15);
        float bv = bias[col];
        int rb = blockIdx.x * 64 + w * 16 + (lane >> 4) * 4;
#pragma unroll
        for (int r = 0; r < 4; ++r) {
            int row = rb + r;
            if (row < N_NODES) {
                float v = acc[n][r] + bv;
                if (outf) outf[(size_t)row * DIM + col] = v;
                else      outb[(size_t)row * DIM + col] = f2bf(v);
            }
        }
    }
}

// ---------------- launch ----------------

extern "C" void kernel_launch(void* const* d_in, const int* in_sizes, int n_in,
                              void* d_out, int out_size, void* d_ws, size_t ws_size,
                              hipStream_t stream) {
    const float* x0    = (const float*)d_in[0];
    const int*   ei    = (const int*)d_in[1];
    const float* Wrel  = (const float*)d_in[2];
    const float* Wroot = (const float*)d_in[3];
    const float* bvec  = (const float*)d_in[4];
    float* out = (float*)d_out;

    char* ws = (char*)d_ws;
    const size_t XB = (size_t)N_NODES * DIM * sizeof(unsigned short);  // 12,800,000
    unsigned short* xbA  = (unsigned short*)ws;
    unsigned short* xbB  = (unsigned short*)(ws + XB);
    // build-time scratch (dead before first layer_fused)
    unsigned int* pairs  = (unsigned int*)(ws + 2 * XB);               // 3.2 MB
    int* bcnt            = (int*)(ws + 2 * XB + 3200000);              // 306,544 B
    int* boff            = (int*)(ws + 2 * XB + 3506944);              // 306,544 B
    int* bucket_start    = (int*)(ws + 2 * XB + 3813504);              // 1,568 B
    unsigned short* Wf   = (unsigned short*)(ws + 3 * XB);             // 196,608 B
    unsigned short* srcs16 = (unsigned short*)(ws + 3 * XB + 196608);  // 1.6 MB
    int* row_start       = (int*)(ws + 3 * XB + 196608 + 1600000);     // 200,004 B

    const int* src = ei;
    const int* dst = ei + N_EDGES;

    convert_x<<<(N_NODES * DIM / 8 + 255) / 256, 256, 0, stream>>>(x0, xbA);
    prep_wf<<<(LAYERS * 4096 + 255) / 256, 256, 0, stream>>>(Wrel, Wroot, Wf);

    bin_count<<<N_CHUNKS, 1024, 0, stream>>>(dst, bcnt);
    bscan<<<1, 512, 0, stream>>>(bcnt, boff, bucket_start);
    bin_scatter<<<N_CHUNKS, 1024, 0, stream>>>(src, dst, bucket_start, boff, pairs);
    fill_lds<<<N_BUCKETS, 1024, 0, stream>>>(pairs, bucket_start, row_start, srcs16);

    unsigned short* xin = xbA;
    unsigned short* xouts[LAYERS] = {xbB, xbA, nullptr};
    const int GRID = (N_NODES + 63) / 64;   // 782
    for (int l = 0; l < LAYERS; ++l) {
        layer_fused<<<GRID, 256, 0, stream>>>(
            xin, row_start, srcs16, Wf + (size_t)l * 32768, bvec + (size_t)l * DIM,
            xouts[l], (l == LAYERS - 1) ? out : nullptr);
        xin = xouts[l];
    }
}